// Round 2
// baseline (3692.942 us; speedup 1.0000x reference)
//
#include <hip/hip_runtime.h>

// x: (B=2, C=128, H=256, W=256); WS=8, NH=16, d=8
#define BB 2
#define CC 128
#define HWSZ 65536
#define RSQE 0.9999950000374997f   // 1/sqrt(1+1e-5)

typedef unsigned short u16;

__device__ __forceinline__ float b2f(u16 u){
  return __uint_as_float(((unsigned int)u) << 16);
}
__device__ __forceinline__ u16 f2b(float f){
  unsigned int v = __float_as_uint(f);
  unsigned int r = (v + 0x7FFFu + ((v >> 16) & 1u)) >> 16;
  return (u16)r;
}

// ---------------- dtype detection: are inputs f32 or bf16? ----------------
// bf16 N(0,1) data: u16 exponent field in [100,141] (outliers ~1e-8 rate).
// f32 data read as u16 pairs: low halves have uniform bits14..7 -> ~84% outliers.
__global__ void k_detect(const u16* __restrict__ xr, int* __restrict__ flag){
  __shared__ int ws_[4];
  int tid = threadIdx.x;
  int cnt = 0;
  for (int i = 0; i < 16; ++i){
    u16 u = xr[tid*16 + i];
    int e = (u >> 7) & 0xFF;
    cnt += (e < 100 || e > 141) ? 1 : 0;
  }
  #pragma unroll
  for (int off = 32; off > 0; off >>= 1) cnt += __shfl_down(cnt, off, 64);
  if ((tid & 63) == 0) ws_[tid >> 6] = cnt;
  __syncthreads();
  if (tid == 0) *flag = (ws_[0]+ws_[1]+ws_[2]+ws_[3] > 64) ? 1 : 0;
}

// ---------------- ingest: canonicalize to bf16 ----------------
__global__ void k_ingest4(const void* __restrict__ src, u16* __restrict__ dst,
                          int n4, const int* __restrict__ flag){
  int i = blockIdx.x * 256 + threadIdx.x;
  if (i >= n4) return;
  if (*flag){
    float4 f = ((const float4*)src)[i];
    ushort4 r; r.x=f2b(f.x); r.y=f2b(f.y); r.z=f2b(f.z); r.w=f2b(f.w);
    ((ushort4*)dst)[i] = r;
  } else {
    ((ushort4*)dst)[i] = ((const ushort4*)src)[i];
  }
}

struct PtrL { const void* p[19]; };

__global__ void k_ingest_w(PtrL pl, u16* __restrict__ dst, const int* __restrict__ flag){
  const int ends[19] = {16384,32768,49152,65536,212992,213120,213248,229632,229760,
                        229888,377344,459264,459392,508544,512144,520336,520464,520592,536976};
  int g = blockIdx.x * 256 + threadIdx.x;
  int idx = g * 4;
  if (idx >= 536976) return;
  int seg = 0, start = 0;
  #pragma unroll
  for (int s = 0; s < 19; ++s){ if (idx >= ends[s]){ seg = s+1; start = ends[s]; } }
  int local = idx - start;
  const void* sp = pl.p[seg];
  if (*flag){
    float4 f = ((const float4*)sp)[local >> 2];
    ushort4 r; r.x=f2b(f.x); r.y=f2b(f.y); r.z=f2b(f.z); r.w=f2b(f.w);
    *(ushort4*)(dst + idx) = r;
  } else {
    *(ushort4*)(dst + idx) = ((const ushort4*)sp)[local >> 2];
  }
}

// ---------------- precompute: channel-attention matrices + combined bias ----------------
__global__ void k_prep_A(const u16* __restrict__ fh, const u16* __restrict__ h1,
                         const u16* __restrict__ fw, const u16* __restrict__ w1,
                         const u16* __restrict__ l1b, const u16* __restrict__ l2b,
                         const u16* __restrict__ fcb,
                         float* __restrict__ A_h, float* __restrict__ A_w,
                         float* __restrict__ biasK){
  int idx = blockIdx.x * 256 + threadIdx.x;      // 16384
  int o = idx >> 7, c = idx & 127;
  float ah = 0.f, aw = 0.f;
  for (int m = 0; m < 128; ++m){
    ah += b2f(fh[o*128 + m]) * b2f(h1[m*128 + c]);
    aw += b2f(fw[o*128 + m]) * b2f(w1[m*128 + c]);
  }
  A_h[idx] = ah; A_w[idx] = aw;
  if (c == 0) biasK[o] = b2f(l1b[o]) + b2f(l2b[o]) + b2f(fcb[o]);
}

// ---------------- precompute: transposed f32 GEMM weights ----------------
__global__ void k_prep_T(const u16* __restrict__ qkv_w, const u16* __restrict__ pw_w,
                         float* __restrict__ At_qkv, float* __restrict__ At_pw){
  int idx = blockIdx.x * 256 + threadIdx.x;      // 65536
  if (idx < 49152){ int r = idx >> 7, k = idx & 127; At_qkv[k*384 + r] = b2f(qkv_w[idx]); }
  else { int j = idx - 49152; int r = j >> 7, k = j & 127; At_pw[k*128 + r] = b2f(pw_w[j]); }
}

// ---------------- precompute: fused 13-tap 5x5 kernel (l1+l2+HGE, bn-scaled) ----------------
__global__ void k_prep_K(const u16* __restrict__ hge_w, const u16* __restrict__ fc_w,
                         const u16* __restrict__ l1_w, const u16* __restrict__ l1_g,
                         const u16* __restrict__ l2_w, const u16* __restrict__ l2_g,
                         float* __restrict__ Kp){
  int idx = blockIdx.x * 256 + threadIdx.x;      // 16384, idx = o*128 + c
  int o = idx >> 7, c = idx & 127;
  float m0=0.f, m45=0.f, m90=0.f, m135=0.f, mgl=0.f;
  const u16* fo = fc_w + o*640;
  for (int m = 0; m < 128; ++m){
    const u16* hw9 = hge_w + (size_t)(m*128 + c)*9;
    m0   += b2f(fo[m      ]) * b2f(hw9[0]);   // S0   = W[:,:,0,0]
    m45  += b2f(fo[128 + m]) * b2f(hw9[1]);   // S45  = W[:,:,0,1]
    m90  += b2f(fo[256 + m]) * b2f(hw9[2]);   // S90  = W[:,:,0,2]
    m135 += b2f(fo[384 + m]) * b2f(hw9[3]);   // S135 = W[:,:,1,0]
    mgl  += b2f(fo[512 + m]) * b2f(hw9[8]);   // GL   = W[:,:,2,2]
  }
  float g1 = b2f(l1_g[o]) * RSQE;
  float g2 = b2f(l2_g[o]) * RSQE;
  float l1v[9];
  #pragma unroll
  for (int t = 0; t < 9; ++t) l1v[t] = b2f(l1_w[(size_t)idx*9 + t]) * g1;
  float l2v = b2f(l2_w[idx]) * g2;
  float* kp = Kp + (size_t)idx*13;
  // taps: (0,2)(1,1)(1,2)(1,3)(2,0)(2,1)(2,2)(2,3)(2,4)(3,1)(3,2)(3,3)(4,2)
  kp[0]  = -0.25f*mgl;
  kp[1]  =  m0 + 2.f*m45 + m90              - 0.25f*mgl + l1v[0];
  kp[2]  =  2.f*m0 + m45 - m135             - 0.50f*mgl + l1v[1];
  kp[3]  =  m0 - m90 - 2.f*m135             - 0.25f*mgl + l1v[2];
  kp[4]  = -0.25f*mgl;
  kp[5]  =  m45 + 2.f*m90 + m135            - 0.50f*mgl + l1v[3];
  kp[6]  =  4.f*mgl + l1v[4] + l2v;
  kp[7]  = -m45 - 2.f*m90 - m135            - 0.50f*mgl + l1v[5];
  kp[8]  = -0.25f*mgl;
  kp[9]  = -m0 + m90 + 2.f*m135             - 0.25f*mgl + l1v[6];
  kp[10] = -2.f*m0 - m45 + m135             - 0.50f*mgl + l1v[7];
  kp[11] = -m0 - 2.f*m45 - m90              - 0.25f*mgl + l1v[8];
  kp[12] = -0.25f*mgl;
}

// ---------------- row/col means of x ----------------
__global__ void k_means(const u16* __restrict__ x, float* __restrict__ mh, float* __restrict__ mw){
  __shared__ float colpart[4][256];
  int c = blockIdx.x, b = blockIdx.y;
  const u16* xp = x + (size_t)(b*CC + c)*HWSZ;
  int tid = threadIdx.x, lane = tid & 63, wv = tid >> 6;
  float c0=0.f,c1=0.f,c2=0.f,c3=0.f;
  for (int r = 0; r < 64; ++r){
    int h = wv*64 + r;
    ushort4 u = *(const ushort4*)(xp + h*256 + lane*4);
    float v0=b2f(u.x), v1=b2f(u.y), v2=b2f(u.z), v3=b2f(u.w);
    c0+=v0; c1+=v1; c2+=v2; c3+=v3;
    float rs = v0+v1+v2+v3;
    #pragma unroll
    for (int off = 32; off > 0; off >>= 1) rs += __shfl_down(rs, off, 64);
    if (lane == 0) mh[(size_t)(b*CC + c)*256 + h] = rs * (1.0f/256.0f);
  }
  colpart[wv][lane*4+0]=c0; colpart[wv][lane*4+1]=c1;
  colpart[wv][lane*4+2]=c2; colpart[wv][lane*4+3]=c3;
  __syncthreads();
  mw[(size_t)(b*CC + c)*256 + tid] =
    (colpart[0][tid]+colpart[1][tid]+colpart[2][tid]+colpart[3][tid]) * (1.0f/256.0f);
}

// ---------------- sigmoid(A @ mean) ----------------
__global__ void k_sig(const float* __restrict__ A_h, const float* __restrict__ A_w,
                      const float* __restrict__ mh, const float* __restrict__ mw,
                      float* __restrict__ s_h, float* __restrict__ s_w){
  int o = blockIdx.x, b = blockIdx.y, sel = blockIdx.z, t = threadIdx.x;
  const float* A = sel ? A_w : A_h;
  const float* m = sel ? mw : mh;
  float* s = sel ? s_w : s_h;
  float acc = 0.f;
  for (int c = 0; c < 128; ++c)
    acc += A[o*128 + c] * m[(size_t)(b*CC + c)*256 + t];
  s[(size_t)(b*CC + o)*256 + t] = 1.0f / (1.0f + __expf(-acc));
}

// ---------------- xs = x * s_h * s_w  (in place on canonical x) ----------------
__global__ void k_scale(const u16* __restrict__ x, const float* __restrict__ s_h,
                        const float* __restrict__ s_w, u16* __restrict__ xs){
  int idx = blockIdx.x * 256 + threadIdx.x;   // 4194304 ushort4 groups
  int w4 = idx & 63; int h = (idx >> 6) & 255; int bc = idx >> 14;
  ushort4 u = ((const ushort4*)x)[idx];
  float sh = s_h[(size_t)bc*256 + h];
  float4 sw = ((const float4*)(s_w + (size_t)bc*256))[w4];
  ushort4 r;
  r.x = f2b(b2f(u.x)*sh*sw.x); r.y = f2b(b2f(u.y)*sh*sw.y);
  r.z = f2b(b2f(u.z)*sh*sw.z); r.w = f2b(b2f(u.w)*sh*sw.w);
  ((ushort4*)xs)[idx] = r;
}

// ---------------- fused "local": 13-tap 5x5 conv, 32x32 tile, 8 oc/block ----------------
__launch_bounds__(256)
__global__ void k_conv5(const u16* __restrict__ xs, const float* __restrict__ Kp,
                        const float* __restrict__ biasK, u16* __restrict__ outp){
  __shared__ float xt[4][36*40];
  int b = blockIdx.z >> 4;
  int oc0 = (blockIdx.z & 15) * 8;
  int h0 = blockIdx.y * 32, w0 = blockIdx.x * 32;
  int tid = threadIdx.x;
  int py = tid >> 4, px = tid & 15;
  float acc[8][4];
  #pragma unroll
  for (int o = 0; o < 8; ++o){ acc[o][0]=0.f; acc[o][1]=0.f; acc[o][2]=0.f; acc[o][3]=0.f; }
  const int DI[13] = {-2,-1,-1,-1, 0, 0,0,0,0, 1,1,1, 2};
  const int DJ[13] = { 0,-1, 0, 1,-2,-1,0,1,2,-1,0,1, 0};
  for (int cc = 0; cc < 128; cc += 4){
    __syncthreads();
    for (int e = tid; e < 5184; e += 256){
      int u = e / 1296; int rem = e - u*1296;
      int r = rem / 36; int q = rem - r*36;
      int ih = h0 - 2 + r, iw = w0 - 2 + q;
      float v = 0.f;
      if ((unsigned)ih < 256u && (unsigned)iw < 256u)
        v = b2f(xs[(size_t)((b*CC + cc + u)*HWSZ) + ih*256 + iw]);
      xt[u][r*40 + q] = v;
    }
    __syncthreads();
    #pragma unroll
    for (int u = 0; u < 4; ++u){
      const float* xb = xt[u];
      const float* kb = Kp + (size_t)(oc0*128 + cc + u)*13;
      #pragma unroll
      for (int t = 0; t < 13; ++t){
        int r = py + DI[t] + 2, q = px + DJ[t] + 2;
        float x00 = xb[r*40 + q];
        float x01 = xb[r*40 + q + 16];
        float x10 = xb[(r+16)*40 + q];
        float x11 = xb[(r+16)*40 + q + 16];
        #pragma unroll
        for (int o = 0; o < 8; ++o){
          float kv = kb[o*1664 + t];
          acc[o][0] += kv*x00; acc[o][1] += kv*x01;
          acc[o][2] += kv*x10; acc[o][3] += kv*x11;
        }
      }
    }
  }
  #pragma unroll
  for (int o = 0; o < 8; ++o){
    float bv = biasK[oc0 + o];
    size_t base = (size_t)((b*CC + oc0 + o)*HWSZ);
    outp[base + (h0+py   )*256 + (w0+px   )] = f2b(acc[o][0] + bv);
    outp[base + (h0+py   )*256 + (w0+px+16)] = f2b(acc[o][1] + bv);
    outp[base + (h0+py+16)*256 + (w0+px   )] = f2b(acc[o][2] + bv);
    outp[base + (h0+py+16)*256 + (w0+px+16)] = f2b(acc[o][3] + bv);
  }
}

// ---------------- tiled GEMM: Y[M][HW] = At^T(128xM) @ X[128][HW] ----------------
// Output: bf16 to Y, unless (Yf != null && *flag) -> f32 to Yf.
__launch_bounds__(256)
__global__ void k_gemm(const float* __restrict__ At, const u16* __restrict__ X,
                       u16* __restrict__ Y, float* __restrict__ Yf, int M,
                       const int* __restrict__ flag){
  __shared__ float As[4096], Xs[4096];
  int n0 = blockIdx.x * 64, m0 = blockIdx.y * 64, bz = blockIdx.z;
  const u16* Xb = X + (size_t)bz * 128 * HWSZ;
  int tid = threadIdx.x;
  int tn = tid & 15, tm = tid >> 4;
  float acc[4][4] = {};
  for (int kc = 0; kc < 128; kc += 64){
    __syncthreads();
    for (int e = tid; e < 4096; e += 256){
      int k = e >> 6, m = e & 63;
      As[e] = At[(size_t)(kc + k)*M + m0 + m];
    }
    for (int e = tid; e < 2048; e += 256){
      int k = e >> 5, j = (e & 31) * 2;
      unsigned int u = *(const unsigned int*)(Xb + (size_t)(kc + k)*HWSZ + n0 + j);
      float2 f; f.x = b2f((u16)(u & 0xffffu)); f.y = b2f((u16)(u >> 16));
      *(float2*)(Xs + k*64 + j) = f;
    }
    __syncthreads();
    #pragma unroll 8
    for (int k = 0; k < 64; ++k){
      float4 a  = *(const float4*)(As + k*64 + tm*4);
      float4 xv = *(const float4*)(Xs + k*64 + tn*4);
      acc[0][0] += a.x*xv.x; acc[0][1] += a.x*xv.y; acc[0][2] += a.x*xv.z; acc[0][3] += a.x*xv.w;
      acc[1][0] += a.y*xv.x; acc[1][1] += a.y*xv.y; acc[1][2] += a.y*xv.z; acc[1][3] += a.y*xv.w;
      acc[2][0] += a.z*xv.x; acc[2][1] += a.z*xv.y; acc[2][2] += a.z*xv.z; acc[2][3] += a.z*xv.w;
      acc[3][0] += a.w*xv.x; acc[3][1] += a.w*xv.y; acc[3][2] += a.w*xv.z; acc[3][3] += a.w*xv.w;
    }
  }
  int f32o = (Yf != nullptr) && (*flag != 0);
  if (f32o){
    float* Yb = Yf + (size_t)bz * (size_t)M * HWSZ;
    #pragma unroll
    for (int i = 0; i < 4; ++i){
      float4 st; st.x=acc[i][0]; st.y=acc[i][1]; st.z=acc[i][2]; st.w=acc[i][3];
      *(float4*)(Yb + (size_t)(m0 + tm*4 + i)*HWSZ + n0 + tn*4) = st;
    }
  } else {
    u16* Yb = Y + (size_t)bz * (size_t)M * HWSZ;
    #pragma unroll
    for (int i = 0; i < 4; ++i){
      ushort4 st;
      st.x = f2b(acc[i][0]); st.y = f2b(acc[i][1]); st.z = f2b(acc[i][2]); st.w = f2b(acc[i][3]);
      *(ushort4*)(Yb + (size_t)(m0 + tm*4 + i)*HWSZ + n0 + tn*4) = st;
    }
  }
}

// ---------------- windowed attention, 8x8 windows, d=8 ----------------
__launch_bounds__(256)
__global__ void k_attn(const u16* __restrict__ qkv, const u16* __restrict__ rel,
                       u16* __restrict__ obuf){
  __shared__ float rell[3600];   // [head][225]
  int tid = threadIdx.x, lane = tid & 63, wv = tid >> 6;
  int b = blockIdx.z, h0 = blockIdx.y*8, w0 = blockIdx.x*8;
  for (int e = tid; e < 3600; e += 256)
    rell[e] = b2f(rel[(e % 225)*16 + e/225]);
  __syncthreads();
  int qi = lane >> 3, qj = lane & 7;
  const u16* qb = qkv + (size_t)b * 384 * HWSZ;
  int poff = (h0 + qi)*256 + (w0 + qj);
  for (int hh = 0; hh < 4; ++hh){
    int head = hh*4 + wv;
    float qr[8], kr[8], vr[8];
    #pragma unroll
    for (int dd = 0; dd < 8; ++dd){
      qr[dd] = b2f(qb[(size_t)(      head*8 + dd)*HWSZ + poff]);
      kr[dd] = b2f(qb[(size_t)(128 + head*8 + dd)*HWSZ + poff]);
      vr[dd] = b2f(qb[(size_t)(256 + head*8 + dd)*HWSZ + poff]);
    }
    const float* rh = rell + head*225;
    float s[64]; float mx = -1e30f;
    #pragma unroll
    for (int kp = 0; kp < 64; ++kp){
      float d = 0.f;
      #pragma unroll
      for (int dd = 0; dd < 8; ++dd) d += qr[dd] * __shfl(kr[dd], kp, 64);
      int ki = kp >> 3, kj = kp & 7;
      float sc = d * 0.35355339059327373f + rh[(qi-ki+7)*15 + (qj-kj+7)];
      s[kp] = sc; mx = fmaxf(mx, sc);
    }
    float sum = 0.f;
    #pragma unroll
    for (int kp = 0; kp < 64; ++kp){ float p = __expf(s[kp]-mx); s[kp] = p; sum += p; }
    float ov[8] = {0.f,0.f,0.f,0.f,0.f,0.f,0.f,0.f};
    #pragma unroll
    for (int kp = 0; kp < 64; ++kp){
      #pragma unroll
      for (int dd = 0; dd < 8; ++dd) ov[dd] += s[kp] * __shfl(vr[dd], kp, 64);
    }
    float inv = 1.0f / sum;
    #pragma unroll
    for (int dd = 0; dd < 8; ++dd)
      obuf[(size_t)(b*CC + head*8 + dd)*HWSZ + poff] = f2b(ov[dd]*inv);
  }
}

// ---------------- u = avgpool_x(o) + avgpool_y(o) + local  (in place over local) ----------------
__global__ void k_pool(const u16* __restrict__ obuf, u16* __restrict__ localb){
  int idx = blockIdx.x * 256 + threadIdx.x;   // 16777216
  int w = idx & 255, h = (idx >> 8) & 255; int bc = idx >> 16;
  const u16* oc_ = obuf + (size_t)bc * HWSZ;
  float sx = 0.f;
  #pragma unroll
  for (int u = 0; u < 8; ++u){
    int t = h - 3 + u;
    if (t == 256) t = 254;
    if ((unsigned)t <= 255u) sx += b2f(oc_[t*256 + w]);
  }
  float sy = 0.f;
  #pragma unroll
  for (int u = 0; u < 8; ++u){
    int t = w - 3 + u;
    if (t == 256) t = 254;
    if ((unsigned)t <= 255u) sy += b2f(oc_[h*256 + t]);
  }
  float res = (sx + sy) * 0.125f + b2f(localb[idx]);
  localb[idx] = f2b(res);
}

// ---------------- depthwise 8x8 conv (reflect edge + zero halo) + bn ----------------
__launch_bounds__(256)
__global__ void k_dw(const u16* __restrict__ u_, const u16* __restrict__ dww,
                     const u16* __restrict__ g, const u16* __restrict__ bta,
                     u16* __restrict__ dwout){
  __shared__ float xt[23][24];
  __shared__ float wt[64];
  int c = blockIdx.z & 127, b = blockIdx.z >> 7;
  int h0 = blockIdx.y*16, w0 = blockIdx.x*16;
  int tid = threadIdx.x;
  const u16* up = u_ + (size_t)(b*CC + c)*HWSZ;
  for (int e = tid; e < 529; e += 256){
    int r = e / 23, q = e - r*23;
    int ih = h0 - 3 + r, iw = w0 - 3 + q;
    if (ih == 256) ih = 254;
    if (iw == 256) iw = 254;
    float v = 0.f;
    if ((unsigned)ih <= 255u && (unsigned)iw <= 255u) v = b2f(up[ih*256 + iw]);
    xt[r][q] = v;
  }
  if (tid < 64) wt[tid] = b2f(dww[c*64 + tid]);
  __syncthreads();
  int py = tid >> 4, px = tid & 15;
  float acc = 0.f;
  #pragma unroll
  for (int i = 0; i < 8; ++i)
    #pragma unroll
    for (int j = 0; j < 8; ++j)
      acc += wt[i*8+j] * xt[py+i][px+j];
  float scale = b2f(g[c]) * RSQE;
  dwout[(size_t)(b*CC + c)*HWSZ + (h0+py)*256 + (w0+px)] = f2b(acc*scale + b2f(bta[c]));
}

// ---------------- launcher ----------------
extern "C" void kernel_launch(void* const* d_in, const int* in_sizes, int n_in,
                              void* d_out, int out_size, void* d_ws, size_t ws_size,
                              hipStream_t stream) {
  // workspace carve-up (~138 MB)
  char* p = (char*)d_ws;
  u16* cx     = (u16*)p; p += 33554432;   // canonical bf16 x; in-place scaled; reused as attn output
  u16* qkvb   = (u16*)p; p += 100663296;  // qkv; reused as depthwise output
  u16* cw     = (u16*)p; p += 1074176;    // canonical bf16 weights (concatenated)
  float* At_qkv = (float*)p; p += 196608;
  float* At_pw  = (float*)p; p += 65536;
  float* A_h    = (float*)p; p += 65536;
  float* A_w    = (float*)p; p += 65536;
  float* Kp     = (float*)p; p += 851968;
  float* biasK  = (float*)p; p += 1024;
  float* mh     = (float*)p; p += 262144;
  float* mw     = (float*)p; p += 262144;
  float* s_h    = (float*)p; p += 262144;
  float* s_w    = (float*)p; p += 262144;
  int* flag     = (int*)p;   p += 256;

  u16* localb = (u16*)d_out;     // d_out doubles as `local` scratch until final GEMM
  u16* obuf   = cx;
  u16* dwbuf  = qkvb;

  // canonical weight offsets (u16 elements) in cw, in d_in order 1..19
  const int O_h1=0, O_w1=16384, O_fh=32768, O_fw=49152, O_l1w=65536, O_l1g=212992,
            O_l1b=213120, O_l2w=213248, O_l2g=229632, O_l2b=229760, O_hge=229888,
            O_fcw=377344, O_fcb=459264, O_qkvw=459392, O_rel=508544, O_dw=512144,
            O_pg=520336, O_pb=520464, O_pw=520592;

  k_detect<<<1, 256, 0, stream>>>((const u16*)d_in[0], flag);
  k_ingest4<<<16384, 256, 0, stream>>>(d_in[0], cx, 4194304, flag);
  PtrL pl;
  for (int i = 0; i < 19; ++i) pl.p[i] = d_in[i+1];
  k_ingest_w<<<525, 256, 0, stream>>>(pl, cw, flag);

  k_prep_A<<<64, 256, 0, stream>>>(cw+O_fh, cw+O_h1, cw+O_fw, cw+O_w1,
                                   cw+O_l1b, cw+O_l2b, cw+O_fcb, A_h, A_w, biasK);
  k_prep_T<<<256, 256, 0, stream>>>(cw+O_qkvw, cw+O_pw, At_qkv, At_pw);
  k_prep_K<<<64, 256, 0, stream>>>(cw+O_hge, cw+O_fcw, cw+O_l1w, cw+O_l1g,
                                   cw+O_l2w, cw+O_l2g, Kp);
  k_means<<<dim3(128, 2), 256, 0, stream>>>(cx, mh, mw);
  k_sig<<<dim3(128, 2, 2), 256, 0, stream>>>(A_h, A_w, mh, mw, s_h, s_w);
  k_scale<<<16384, 256, 0, stream>>>(cx, s_h, s_w, cx);
  k_conv5<<<dim3(8, 8, 32), 256, 0, stream>>>(cx, Kp, biasK, localb);
  k_gemm<<<dim3(1024, 6, 2), 256, 0, stream>>>(At_qkv, cx, qkvb, nullptr, 384, flag);
  k_attn<<<dim3(32, 32, 2), 256, 0, stream>>>(qkvb, cw+O_rel, obuf);
  k_pool<<<65536, 256, 0, stream>>>(obuf, localb);
  k_dw<<<dim3(16, 16, 256), 256, 0, stream>>>(localb, cw+O_dw, cw+O_pg, cw+O_pb, dwbuf);
  k_gemm<<<dim3(1024, 2, 2), 256, 0, stream>>>(At_pw, dwbuf, (u16*)d_out, (float*)d_out, 128, flag);
}

// Round 3
// 1436.660 us; speedup vs baseline: 2.5705x; 2.5705x over previous
//
#include <hip/hip_runtime.h>

// x: (B=2, C=128, H=256, W=256); WS=8, NH=16, d=8
#define BB 2
#define CC 128
#define HWSZ 65536
#define RSQE 0.9999950000374997f   // 1/sqrt(1+1e-5)

typedef unsigned short u16;
using short8 = __attribute__((ext_vector_type(8))) short;
using f32x4  = __attribute__((ext_vector_type(4))) float;

__device__ __forceinline__ float b2f(u16 u){
  return __uint_as_float(((unsigned int)u) << 16);
}
__device__ __forceinline__ u16 f2b(float f){
  unsigned int v = __float_as_uint(f);
  unsigned int r = (v + 0x7FFFu + ((v >> 16) & 1u)) >> 16;
  return (u16)r;
}

// tap offsets for the fused 13-tap 5x5 kernel (order matches k_prep_K)
__device__ const int c_DI[13] = {-2,-1,-1,-1, 0, 0,0,0,0, 1,1,1, 2};
__device__ const int c_DJ[13] = { 0,-1, 0, 1,-2,-1,0,1,2,-1,0,1, 0};

// ---------------- dtype detection: are inputs f32 or bf16? ----------------
__global__ void k_detect(const u16* __restrict__ xr, int* __restrict__ flag){
  __shared__ int ws_[4];
  int tid = threadIdx.x;
  int cnt = 0;
  for (int i = 0; i < 16; ++i){
    u16 u = xr[tid*16 + i];
    int e = (u >> 7) & 0xFF;
    cnt += (e < 100 || e > 141) ? 1 : 0;
  }
  #pragma unroll
  for (int off = 32; off > 0; off >>= 1) cnt += __shfl_down(cnt, off, 64);
  if ((tid & 63) == 0) ws_[tid >> 6] = cnt;
  __syncthreads();
  if (tid == 0) *flag = (ws_[0]+ws_[1]+ws_[2]+ws_[3] > 64) ? 1 : 0;
}

// ---------------- ingest: canonicalize to bf16 ----------------
__global__ void k_ingest4(const void* __restrict__ src, u16* __restrict__ dst,
                          int n4, const int* __restrict__ flag){
  int i = blockIdx.x * 256 + threadIdx.x;
  if (i >= n4) return;
  if (*flag){
    float4 f = ((const float4*)src)[i];
    ushort4 r; r.x=f2b(f.x); r.y=f2b(f.y); r.z=f2b(f.z); r.w=f2b(f.w);
    ((ushort4*)dst)[i] = r;
  } else {
    ((ushort4*)dst)[i] = ((const ushort4*)src)[i];
  }
}

struct PtrL { const void* p[19]; };

__global__ void k_ingest_w(PtrL pl, u16* __restrict__ dst, const int* __restrict__ flag){
  const int ends[19] = {16384,32768,49152,65536,212992,213120,213248,229632,229760,
                        229888,377344,459264,459392,508544,512144,520336,520464,520592,536976};
  int g = blockIdx.x * 256 + threadIdx.x;
  int idx = g * 4;
  if (idx >= 536976) return;
  int seg = 0, start = 0;
  #pragma unroll
  for (int s = 0; s < 19; ++s){ if (idx >= ends[s]){ seg = s+1; start = ends[s]; } }
  int local = idx - start;
  const void* sp = pl.p[seg];
  if (*flag){
    float4 f = ((const float4*)sp)[local >> 2];
    ushort4 r; r.x=f2b(f.x); r.y=f2b(f.y); r.z=f2b(f.z); r.w=f2b(f.w);
    *(ushort4*)(dst + idx) = r;
  } else {
    *(ushort4*)(dst + idx) = ((const ushort4*)sp)[local >> 2];
  }
}

// ---------------- precompute: channel-attention matrices + combined bias ----------------
__global__ void k_prep_A(const u16* __restrict__ fh, const u16* __restrict__ h1,
                         const u16* __restrict__ fw, const u16* __restrict__ w1,
                         const u16* __restrict__ l1b, const u16* __restrict__ l2b,
                         const u16* __restrict__ fcb,
                         float* __restrict__ A_h, float* __restrict__ A_w,
                         float* __restrict__ biasK){
  int idx = blockIdx.x * 256 + threadIdx.x;      // 16384
  int o = idx >> 7, c = idx & 127;
  float ah = 0.f, aw = 0.f;
  for (int m = 0; m < 128; ++m){
    ah += b2f(fh[o*128 + m]) * b2f(h1[m*128 + c]);
    aw += b2f(fw[o*128 + m]) * b2f(w1[m*128 + c]);
  }
  A_h[idx] = ah; A_w[idx] = aw;
  if (c == 0) biasK[o] = b2f(l1b[o]) + b2f(l2b[o]) + b2f(fcb[o]);
}

// ---------------- precompute: transposed f32 GEMM weights ----------------
__global__ void k_prep_T(const u16* __restrict__ qkv_w, const u16* __restrict__ pw_w,
                         float* __restrict__ At_qkv, float* __restrict__ At_pw){
  int idx = blockIdx.x * 256 + threadIdx.x;      // 65536
  if (idx < 49152){ int r = idx >> 7, k = idx & 127; At_qkv[k*384 + r] = b2f(qkv_w[idx]); }
  else { int j = idx - 49152; int r = j >> 7, k = j & 127; At_pw[k*128 + r] = b2f(pw_w[j]); }
}

// ---------------- precompute: fused 13-tap kernel in bf16 [t][oc][ic] ----------------
__global__ void k_prep_K(const u16* __restrict__ hge_w, const u16* __restrict__ fc_w,
                         const u16* __restrict__ l1_w, const u16* __restrict__ l1_g,
                         const u16* __restrict__ l2_w, const u16* __restrict__ l2_g,
                         u16* __restrict__ Kwb){
  int idx = blockIdx.x * 256 + threadIdx.x;      // 16384, idx = o*128 + c
  int o = idx >> 7, c = idx & 127;
  float m0=0.f, m45=0.f, m90=0.f, m135=0.f, mgl=0.f;
  const u16* fo = fc_w + o*640;
  for (int m = 0; m < 128; ++m){
    const u16* hw9 = hge_w + (size_t)(m*128 + c)*9;
    m0   += b2f(fo[m      ]) * b2f(hw9[0]);   // S0   = W[:,:,0,0]
    m45  += b2f(fo[128 + m]) * b2f(hw9[1]);   // S45  = W[:,:,0,1]
    m90  += b2f(fo[256 + m]) * b2f(hw9[2]);   // S90  = W[:,:,0,2]
    m135 += b2f(fo[384 + m]) * b2f(hw9[3]);   // S135 = W[:,:,1,0]
    mgl  += b2f(fo[512 + m]) * b2f(hw9[8]);   // GL   = W[:,:,2,2]
  }
  float g1 = b2f(l1_g[o]) * RSQE;
  float g2 = b2f(l2_g[o]) * RSQE;
  float l1v[9];
  #pragma unroll
  for (int t = 0; t < 9; ++t) l1v[t] = b2f(l1_w[(size_t)idx*9 + t]) * g1;
  float l2v = b2f(l2_w[idx]) * g2;
  float kp[13];
  // taps: (-2,0)(-1,-1)(-1,0)(-1,1)(0,-2)(0,-1)(0,0)(0,1)(0,2)(1,-1)(1,0)(1,1)(2,0)
  kp[0]  = -0.25f*mgl;
  kp[1]  =  m0 + 2.f*m45 + m90              - 0.25f*mgl + l1v[0];
  kp[2]  =  2.f*m0 + m45 - m135             - 0.50f*mgl + l1v[1];
  kp[3]  =  m0 - m90 - 2.f*m135             - 0.25f*mgl + l1v[2];
  kp[4]  = -0.25f*mgl;
  kp[5]  =  m45 + 2.f*m90 + m135            - 0.50f*mgl + l1v[3];
  kp[6]  =  4.f*mgl + l1v[4] + l2v;
  kp[7]  = -m45 - 2.f*m90 - m135            - 0.50f*mgl + l1v[5];
  kp[8]  = -0.25f*mgl;
  kp[9]  = -m0 + m90 + 2.f*m135             - 0.25f*mgl + l1v[6];
  kp[10] = -2.f*m0 - m45 + m135             - 0.50f*mgl + l1v[7];
  kp[11] = -m0 - 2.f*m45 - m90              - 0.25f*mgl + l1v[8];
  kp[12] = -0.25f*mgl;
  #pragma unroll
  for (int t = 0; t < 13; ++t) Kwb[t*16384 + idx] = f2b(kp[t]);   // [t][oc][ic]
}

// ---------------- row/col means of x ----------------
__global__ void k_means(const u16* __restrict__ x, float* __restrict__ mh, float* __restrict__ mw){
  __shared__ float colpart[4][256];
  int c = blockIdx.x, b = blockIdx.y;
  const u16* xp = x + (size_t)(b*CC + c)*HWSZ;
  int tid = threadIdx.x, lane = tid & 63, wv = tid >> 6;
  float c0=0.f,c1=0.f,c2=0.f,c3=0.f;
  for (int r = 0; r < 64; ++r){
    int h = wv*64 + r;
    ushort4 u = *(const ushort4*)(xp + h*256 + lane*4);
    float v0=b2f(u.x), v1=b2f(u.y), v2=b2f(u.z), v3=b2f(u.w);
    c0+=v0; c1+=v1; c2+=v2; c3+=v3;
    float rs = v0+v1+v2+v3;
    #pragma unroll
    for (int off = 32; off > 0; off >>= 1) rs += __shfl_down(rs, off, 64);
    if (lane == 0) mh[(size_t)(b*CC + c)*256 + h] = rs * (1.0f/256.0f);
  }
  colpart[wv][lane*4+0]=c0; colpart[wv][lane*4+1]=c1;
  colpart[wv][lane*4+2]=c2; colpart[wv][lane*4+3]=c3;
  __syncthreads();
  mw[(size_t)(b*CC + c)*256 + tid] =
    (colpart[0][tid]+colpart[1][tid]+colpart[2][tid]+colpart[3][tid]) * (1.0f/256.0f);
}

// ---------------- sigmoid(A @ mean) ----------------
__global__ void k_sig(const float* __restrict__ A_h, const float* __restrict__ A_w,
                      const float* __restrict__ mh, const float* __restrict__ mw,
                      float* __restrict__ s_h, float* __restrict__ s_w){
  int o = blockIdx.x, b = blockIdx.y, sel = blockIdx.z, t = threadIdx.x;
  const float* A = sel ? A_w : A_h;
  const float* m = sel ? mw : mh;
  float* s = sel ? s_w : s_h;
  float acc = 0.f;
  for (int c = 0; c < 128; ++c)
    acc += A[o*128 + c] * m[(size_t)(b*CC + c)*256 + t];
  s[(size_t)(b*CC + o)*256 + t] = 1.0f / (1.0f + __expf(-acc));
}

// ---------------- xs = x * s_h * s_w  (in place on canonical x) ----------------
__global__ void k_scale(const u16* __restrict__ x, const float* __restrict__ s_h,
                        const float* __restrict__ s_w, u16* __restrict__ xs){
  int idx = blockIdx.x * 256 + threadIdx.x;   // 4194304 ushort4 groups
  int w4 = idx & 63; int h = (idx >> 6) & 255; int bc = idx >> 14;
  ushort4 u = ((const ushort4*)x)[idx];
  float sh = s_h[(size_t)bc*256 + h];
  float4 sw = ((const float4*)(s_w + (size_t)bc*256))[w4];
  ushort4 r;
  r.x = f2b(b2f(u.x)*sh*sw.x); r.y = f2b(b2f(u.y)*sh*sw.y);
  r.z = f2b(b2f(u.z)*sh*sw.z); r.w = f2b(b2f(u.w)*sh*sw.w);
  ((ushort4*)xs)[idx] = r;
}

// ---------------- channels-first -> channels-last padded [b][260][260][128] ----------------
__global__ void k_cf2cl(const u16* __restrict__ cx, u16* __restrict__ xcl){
  __shared__ u16 t[16][136];   // [w][ic], padded
  int b = blockIdx.z >> 8, h = blockIdx.z & 255;
  int w0 = blockIdx.x * 16;
  int tid = threadIdx.x;
  // load: ic = tid>>1 (0..127), wseg = (tid&1)*8 -> 8 w's (16B)
  int ic = tid >> 1, wseg = (tid & 1) * 8;
  uint4 v = *(const uint4*)(cx + (size_t)(b*CC + ic)*HWSZ + h*256 + w0 + wseg);
  u16 tmp[8]; *(uint4*)tmp = v;
  #pragma unroll
  for (int k = 0; k < 8; ++k) t[wseg + k][ic] = tmp[k];
  __syncthreads();
  // store: w = tid>>4 (0..15), part = (tid&15)*8 -> 8 ic (16B), coalesced
  int w = tid >> 4, part = (tid & 15) * 8;
  uint4 o = *(const uint4*)&t[w][part];
  *(uint4*)(xcl + (((size_t)(b*260 + h + 2))*260 + (w0 + w + 2))*128 + part) = o;
}

// ---------------- MFMA implicit-GEMM conv: M=pixels, N=oc(128), K=13*128 ----------------
__launch_bounds__(256)
__global__ void k_conv5m(const u16* __restrict__ xcl, const u16* __restrict__ Kwb,
                         const float* __restrict__ biasK, u16* __restrict__ outp){
  __shared__ u16 As[128][40];   // [pixel][k-chunk], +8 pad
  __shared__ u16 Bs[128][40];   // [oc][k-chunk], +8 pad
  int tid = threadIdx.x;
  int wv = tid >> 6, lane = tid & 63;
  int q = lane >> 4, l16 = lane & 15;
  int pt = blockIdx.x;                 // 1024 tiles of 128 pixels
  int b = pt >> 9;
  int h = (pt >> 1) & 255;
  int w0 = (pt & 1) << 7;
  int mrow = (wv & 1) << 6;
  int nrow = (wv >> 1) << 6;
  int sr = tid >> 2, sp = (tid & 3) << 3;   // stage: row, elem-part
  f32x4 acc[4][4];
  #pragma unroll
  for (int mt = 0; mt < 4; ++mt)
    #pragma unroll
    for (int nt = 0; nt < 4; ++nt) acc[mt][nt] = (f32x4){0.f,0.f,0.f,0.f};

  for (int kc = 0; kc < 52; ++kc){
    int t = kc >> 2, c0 = (kc & 3) << 5;
    int di = c_DI[t], dj = c_DJ[t];
    const u16* Ab = xcl + (((size_t)(b*260 + h + 2 + di))*260 + (w0 + 2 + dj))*128 + c0;
    const u16* Bb = Kwb + t*16384 + c0;
    __syncthreads();
    {
      // A: 128 rows x 32 elems; rows 0..63 then 64..127
      uint4 va0 = *(const uint4*)(Ab + (size_t)sr*128 + sp);
      uint4 va1 = *(const uint4*)(Ab + (size_t)(sr + 64)*128 + sp);
      *(uint4*)&As[sr][sp] = va0;
      *(uint4*)&As[sr + 64][sp] = va1;
      uint4 vb0 = *(const uint4*)(Bb + sr*128 + sp);
      uint4 vb1 = *(const uint4*)(Bb + (sr + 64)*128 + sp);
      *(uint4*)&Bs[sr][sp] = vb0;
      *(uint4*)&Bs[sr + 64][sp] = vb1;
    }
    __syncthreads();
    short8 af[4], bf[4];
    #pragma unroll
    for (int mt = 0; mt < 4; ++mt) af[mt] = *(const short8*)&As[mrow + mt*16 + l16][q*8];
    #pragma unroll
    for (int nt = 0; nt < 4; ++nt) bf[nt] = *(const short8*)&Bs[nrow + nt*16 + l16][q*8];
    #pragma unroll
    for (int mt = 0; mt < 4; ++mt)
      #pragma unroll
      for (int nt = 0; nt < 4; ++nt)
        acc[mt][nt] = __builtin_amdgcn_mfma_f32_16x16x32_bf16(af[mt], bf[nt], acc[mt][nt], 0, 0, 0);
  }
  // epilogue: C/D layout col(n=oc)=lane&15, row(m=pixel)=q*4+reg
  #pragma unroll
  for (int nt = 0; nt < 4; ++nt){
    int n = nrow + nt*16 + l16;
    float bv = biasK[n];
    size_t cbase = (size_t)(b*CC + n)*HWSZ + h*256 + w0;
    #pragma unroll
    for (int mt = 0; mt < 4; ++mt){
      int m = mrow + mt*16 + q*4;
      ushort4 st;
      st.x = f2b(acc[mt][nt][0] + bv);
      st.y = f2b(acc[mt][nt][1] + bv);
      st.z = f2b(acc[mt][nt][2] + bv);
      st.w = f2b(acc[mt][nt][3] + bv);
      *(ushort4*)(outp + cbase + m) = st;
    }
  }
}

// ---------------- tiled GEMM: Y[M][HW] = At^T(128xM) @ X[128][HW] ----------------
__launch_bounds__(256)
__global__ void k_gemm(const float* __restrict__ At, const u16* __restrict__ X,
                       u16* __restrict__ Y, float* __restrict__ Yf, int M,
                       const int* __restrict__ flag){
  __shared__ float As[4096], Xs[4096];
  int n0 = blockIdx.x * 64, m0 = blockIdx.y * 64, bz = blockIdx.z;
  const u16* Xb = X + (size_t)bz * 128 * HWSZ;
  int tid = threadIdx.x;
  int tn = tid & 15, tm = tid >> 4;
  float acc[4][4] = {};
  for (int kc = 0; kc < 128; kc += 64){
    __syncthreads();
    for (int e = tid; e < 4096; e += 256){
      int k = e >> 6, m = e & 63;
      As[e] = At[(size_t)(kc + k)*M + m0 + m];
    }
    for (int e = tid; e < 2048; e += 256){
      int k = e >> 5, j = (e & 31) * 2;
      unsigned int u = *(const unsigned int*)(Xb + (size_t)(kc + k)*HWSZ + n0 + j);
      float2 f; f.x = b2f((u16)(u & 0xffffu)); f.y = b2f((u16)(u >> 16));
      *(float2*)(Xs + k*64 + j) = f;
    }
    __syncthreads();
    #pragma unroll 8
    for (int k = 0; k < 64; ++k){
      float4 a  = *(const float4*)(As + k*64 + tm*4);
      float4 xv = *(const float4*)(Xs + k*64 + tn*4);
      acc[0][0] += a.x*xv.x; acc[0][1] += a.x*xv.y; acc[0][2] += a.x*xv.z; acc[0][3] += a.x*xv.w;
      acc[1][0] += a.y*xv.x; acc[1][1] += a.y*xv.y; acc[1][2] += a.y*xv.z; acc[1][3] += a.y*xv.w;
      acc[2][0] += a.z*xv.x; acc[2][1] += a.z*xv.y; acc[2][2] += a.z*xv.z; acc[2][3] += a.z*xv.w;
      acc[3][0] += a.w*xv.x; acc[3][1] += a.w*xv.y; acc[3][2] += a.w*xv.z; acc[3][3] += a.w*xv.w;
    }
  }
  int f32o = (Yf != nullptr) && (*flag != 0);
  if (f32o){
    float* Yb = Yf + (size_t)bz * (size_t)M * HWSZ;
    #pragma unroll
    for (int i = 0; i < 4; ++i){
      float4 st; st.x=acc[i][0]; st.y=acc[i][1]; st.z=acc[i][2]; st.w=acc[i][3];
      *(float4*)(Yb + (size_t)(m0 + tm*4 + i)*HWSZ + n0 + tn*4) = st;
    }
  } else {
    u16* Yb = Y + (size_t)bz * (size_t)M * HWSZ;
    #pragma unroll
    for (int i = 0; i < 4; ++i){
      ushort4 st;
      st.x = f2b(acc[i][0]); st.y = f2b(acc[i][1]); st.z = f2b(acc[i][2]); st.w = f2b(acc[i][3]);
      *(ushort4*)(Yb + (size_t)(m0 + tm*4 + i)*HWSZ + n0 + tn*4) = st;
    }
  }
}

// ---------------- windowed attention, 8x8 windows, d=8 ----------------
__launch_bounds__(256)
__global__ void k_attn(const u16* __restrict__ qkv, const u16* __restrict__ rel,
                       u16* __restrict__ obuf){
  __shared__ float rell[3600];   // [head][225]
  int tid = threadIdx.x, lane = tid & 63, wv = tid >> 6;
  int b = blockIdx.z, h0 = blockIdx.y*8, w0 = blockIdx.x*8;
  for (int e = tid; e < 3600; e += 256)
    rell[e] = b2f(rel[(e % 225)*16 + e/225]);
  __syncthreads();
  int qi = lane >> 3, qj = lane & 7;
  const u16* qb = qkv + (size_t)b * 384 * HWSZ;
  int poff = (h0 + qi)*256 + (w0 + qj);
  for (int hh = 0; hh < 4; ++hh){
    int head = hh*4 + wv;
    float qr[8], kr[8], vr[8];
    #pragma unroll
    for (int dd = 0; dd < 8; ++dd){
      qr[dd] = b2f(qb[(size_t)(      head*8 + dd)*HWSZ + poff]);
      kr[dd] = b2f(qb[(size_t)(128 + head*8 + dd)*HWSZ + poff]);
      vr[dd] = b2f(qb[(size_t)(256 + head*8 + dd)*HWSZ + poff]);
    }
    const float* rh = rell + head*225;
    float s[64]; float mx = -1e30f;
    #pragma unroll
    for (int kp = 0; kp < 64; ++kp){
      float d = 0.f;
      #pragma unroll
      for (int dd = 0; dd < 8; ++dd) d += qr[dd] * __shfl(kr[dd], kp, 64);
      int ki = kp >> 3, kj = kp & 7;
      float sc = d * 0.35355339059327373f + rh[(qi-ki+7)*15 + (qj-kj+7)];
      s[kp] = sc; mx = fmaxf(mx, sc);
    }
    float sum = 0.f;
    #pragma unroll
    for (int kp = 0; kp < 64; ++kp){ float p = __expf(s[kp]-mx); s[kp] = p; sum += p; }
    float ov[8] = {0.f,0.f,0.f,0.f,0.f,0.f,0.f,0.f};
    #pragma unroll
    for (int kp = 0; kp < 64; ++kp){
      #pragma unroll
      for (int dd = 0; dd < 8; ++dd) ov[dd] += s[kp] * __shfl(vr[dd], kp, 64);
    }
    float inv = 1.0f / sum;
    #pragma unroll
    for (int dd = 0; dd < 8; ++dd)
      obuf[(size_t)(b*CC + head*8 + dd)*HWSZ + poff] = f2b(ov[dd]*inv);
  }
}

// ---------------- u = avgpool_x(o) + avgpool_y(o) + local ----------------
__global__ void k_pool(const u16* __restrict__ obuf, u16* __restrict__ localb){
  int idx = blockIdx.x * 256 + threadIdx.x;   // 16777216
  int w = idx & 255, h = (idx >> 8) & 255; int bc = idx >> 16;
  const u16* oc_ = obuf + (size_t)bc * HWSZ;
  float sx = 0.f;
  #pragma unroll
  for (int u = 0; u < 8; ++u){
    int t = h - 3 + u;
    if (t == 256) t = 254;
    if ((unsigned)t <= 255u) sx += b2f(oc_[t*256 + w]);
  }
  float sy = 0.f;
  #pragma unroll
  for (int u = 0; u < 8; ++u){
    int t = w - 3 + u;
    if (t == 256) t = 254;
    if ((unsigned)t <= 255u) sy += b2f(oc_[h*256 + t]);
  }
  float res = (sx + sy) * 0.125f + b2f(localb[idx]);
  localb[idx] = f2b(res);
}

// ---------------- depthwise 8x8 conv (reflect edge + zero halo) + bn ----------------
__launch_bounds__(256)
__global__ void k_dw(const u16* __restrict__ u_, const u16* __restrict__ dww,
                     const u16* __restrict__ g, const u16* __restrict__ bta,
                     u16* __restrict__ dwout){
  __shared__ float xt[23][24];
  __shared__ float wt[64];
  int c = blockIdx.z & 127, b = blockIdx.z >> 7;
  int h0 = blockIdx.y*16, w0 = blockIdx.x*16;
  int tid = threadIdx.x;
  const u16* up = u_ + (size_t)(b*CC + c)*HWSZ;
  for (int e = tid; e < 529; e += 256){
    int r = e / 23, q = e - r*23;
    int ih = h0 - 3 + r, iw = w0 - 3 + q;
    if (ih == 256) ih = 254;
    if (iw == 256) iw = 254;
    float v = 0.f;
    if ((unsigned)ih <= 255u && (unsigned)iw <= 255u) v = b2f(up[ih*256 + iw]);
    xt[r][q] = v;
  }
  if (tid < 64) wt[tid] = b2f(dww[c*64 + tid]);
  __syncthreads();
  int py = tid >> 4, px = tid & 15;
  float acc = 0.f;
  #pragma unroll
  for (int i = 0; i < 8; ++i)
    #pragma unroll
    for (int j = 0; j < 8; ++j)
      acc += wt[i*8+j] * xt[py+i][px+j];
  float scale = b2f(g[c]) * RSQE;
  dwout[(size_t)(b*CC + c)*HWSZ + (h0+py)*256 + (w0+px)] = f2b(acc*scale + b2f(bta[c]));
}

// ---------------- launcher ----------------
extern "C" void kernel_launch(void* const* d_in, const int* in_sizes, int n_in,
                              void* d_out, int out_size, void* d_ws, size_t ws_size,
                              hipStream_t stream) {
  // workspace carve-up (~137 MB)
  char* p = (char*)d_ws;
  u16* cx     = (u16*)p; p += 33554432;   // canonical bf16 x; in-place scaled; reused as attn output
  u16* qkvb   = (u16*)p; p += 100663296;  // xcl (padded CL image) -> qkv -> depthwise output
  u16* cw     = (u16*)p; p += 1074176;    // canonical bf16 weights (concatenated)
  float* At_qkv = (float*)p; p += 196608;
  float* At_pw  = (float*)p; p += 65536;
  float* A_h    = (float*)p; p += 65536;
  float* A_w    = (float*)p; p += 65536;
  u16*  Kwb     = (u16*)p;  p += 425984;  // [13][128][128] bf16
  float* biasK  = (float*)p; p += 1024;
  float* mh     = (float*)p; p += 262144;
  float* mw     = (float*)p; p += 262144;
  float* s_h    = (float*)p; p += 262144;
  float* s_w    = (float*)p; p += 262144;
  int* flag     = (int*)p;   p += 256;

  u16* localb = (u16*)d_out;     // d_out doubles as `local` scratch until final GEMM
  u16* xcl    = qkvb;            // padded channels-last image, dead before qkv GEMM writes
  u16* obuf   = cx;
  u16* dwbuf  = qkvb;

  const int O_h1=0, O_w1=16384, O_fh=32768, O_fw=49152, O_l1w=65536, O_l1g=212992,
            O_l1b=213120, O_l2w=213248, O_l2g=229632, O_l2b=229760, O_hge=229888,
            O_fcw=377344, O_fcb=459264, O_qkvw=459392, O_rel=508544, O_dw=512144,
            O_pg=520336, O_pb=520464, O_pw=520592;

  k_detect<<<1, 256, 0, stream>>>((const u16*)d_in[0], flag);
  k_ingest4<<<16384, 256, 0, stream>>>(d_in[0], cx, 4194304, flag);
  PtrL pl;
  for (int i = 0; i < 19; ++i) pl.p[i] = d_in[i+1];
  k_ingest_w<<<525, 256, 0, stream>>>(pl, cw, flag);

  k_prep_A<<<64, 256, 0, stream>>>(cw+O_fh, cw+O_h1, cw+O_fw, cw+O_w1,
                                   cw+O_l1b, cw+O_l2b, cw+O_fcb, A_h, A_w, biasK);
  k_prep_T<<<256, 256, 0, stream>>>(cw+O_qkvw, cw+O_pw, At_qkv, At_pw);
  k_prep_K<<<64, 256, 0, stream>>>(cw+O_hge, cw+O_fcw, cw+O_l1w, cw+O_l1g,
                                   cw+O_l2w, cw+O_l2g, Kwb);
  k_means<<<dim3(128, 2), 256, 0, stream>>>(cx, mh, mw);
  k_sig<<<dim3(128, 2, 2), 256, 0, stream>>>(A_h, A_w, mh, mw, s_h, s_w);
  k_scale<<<16384, 256, 0, stream>>>(cx, s_h, s_w, cx);

  // padded channels-last staging for the MFMA conv
  hipMemsetAsync(xcl, 0, (size_t)2*260*260*128*2, stream);
  k_cf2cl<<<dim3(16, 1, 512), 256, 0, stream>>>(cx, xcl);
  k_conv5m<<<1024, 256, 0, stream>>>(xcl, Kwb, biasK, localb);

  k_gemm<<<dim3(1024, 6, 2), 256, 0, stream>>>(At_qkv, cx, qkvb, nullptr, 384, flag);
  k_attn<<<dim3(32, 32, 2), 256, 0, stream>>>(qkvb, cw+O_rel, obuf);
  k_pool<<<65536, 256, 0, stream>>>(obuf, localb);
  k_dw<<<dim3(16, 16, 256), 256, 0, stream>>>(localb, cw+O_dw, cw+O_pg, cw+O_pb, dwbuf);
  k_gemm<<<dim3(1024, 2, 2), 256, 0, stream>>>(At_pw, dwbuf, (u16*)d_out, (float*)d_out, 128, flag);
}

// Round 4
// 1029.302 us; speedup vs baseline: 3.5878x; 1.3958x over previous
//
#include <hip/hip_runtime.h>

// x: (B=2, C=128, H=256, W=256); WS=8, NH=16, d=8
#define BB 2
#define CC 128
#define HWSZ 65536
#define RSQE 0.9999950000374997f   // 1/sqrt(1+1e-5)
#define ATT_SCALE 0.35355339059327373f

typedef unsigned short u16;
using short8 = __attribute__((ext_vector_type(8))) short;
using f32x4  = __attribute__((ext_vector_type(4))) float;

#if defined(__has_builtin)
# if __has_builtin(__builtin_amdgcn_fdot2_f32_bf16)
#  define HAVE_DOT2 1
# endif
#endif

__device__ __forceinline__ float b2f(u16 u){
  return __uint_as_float(((unsigned int)u) << 16);
}
__device__ __forceinline__ u16 f2b(float f){
  unsigned int v = __float_as_uint(f);
  unsigned int r = (v + 0x7FFFu + ((v >> 16) & 1u)) >> 16;
  return (u16)r;
}

// tap offsets for the fused 13-tap 5x5 kernel (order matches k_prep_K)
__device__ const int c_DI[13] = {-2,-1,-1,-1, 0, 0,0,0,0, 1,1,1, 2};
__device__ const int c_DJ[13] = { 0,-1, 0, 1,-2,-1,0,1,2,-1,0,1, 0};

// ---------------- dtype detection ----------------
__global__ void k_detect(const u16* __restrict__ xr, int* __restrict__ flag){
  __shared__ int ws_[4];
  int tid = threadIdx.x;
  int cnt = 0;
  for (int i = 0; i < 16; ++i){
    u16 u = xr[tid*16 + i];
    int e = (u >> 7) & 0xFF;
    cnt += (e < 100 || e > 141) ? 1 : 0;
  }
  #pragma unroll
  for (int off = 32; off > 0; off >>= 1) cnt += __shfl_down(cnt, off, 64);
  if ((tid & 63) == 0) ws_[tid >> 6] = cnt;
  __syncthreads();
  if (tid == 0) *flag = (ws_[0]+ws_[1]+ws_[2]+ws_[3] > 64) ? 1 : 0;
}

// ---------------- ingest ----------------
__global__ void k_ingest4(const void* __restrict__ src, u16* __restrict__ dst,
                          int n4, const int* __restrict__ flag){
  int i = blockIdx.x * 256 + threadIdx.x;
  if (i >= n4) return;
  if (*flag){
    float4 f = ((const float4*)src)[i];
    ushort4 r; r.x=f2b(f.x); r.y=f2b(f.y); r.z=f2b(f.z); r.w=f2b(f.w);
    ((ushort4*)dst)[i] = r;
  } else {
    ((ushort4*)dst)[i] = ((const ushort4*)src)[i];
  }
}

struct PtrL { const void* p[19]; };

__global__ void k_ingest_w(PtrL pl, u16* __restrict__ dst, const int* __restrict__ flag){
  const int ends[19] = {16384,32768,49152,65536,212992,213120,213248,229632,229760,
                        229888,377344,459264,459392,508544,512144,520336,520464,520592,536976};
  int g = blockIdx.x * 256 + threadIdx.x;
  int idx = g * 4;
  if (idx >= 536976) return;
  int seg = 0, start = 0;
  #pragma unroll
  for (int s = 0; s < 19; ++s){ if (idx >= ends[s]){ seg = s+1; start = ends[s]; } }
  int local = idx - start;
  const void* sp = pl.p[seg];
  if (*flag){
    float4 f = ((const float4*)sp)[local >> 2];
    ushort4 r; r.x=f2b(f.x); r.y=f2b(f.y); r.z=f2b(f.z); r.w=f2b(f.w);
    *(ushort4*)(dst + idx) = r;
  } else {
    *(ushort4*)(dst + idx) = ((const ushort4*)sp)[local >> 2];
  }
}

// ---------------- precompute: channel-attention matrices + combined bias ----------------
__global__ void k_prep_A(const u16* __restrict__ fh, const u16* __restrict__ h1,
                         const u16* __restrict__ fw, const u16* __restrict__ w1,
                         const u16* __restrict__ l1b, const u16* __restrict__ l2b,
                         const u16* __restrict__ fcb,
                         float* __restrict__ A_h, float* __restrict__ A_w,
                         float* __restrict__ biasK){
  int idx = blockIdx.x * 256 + threadIdx.x;
  int o = idx >> 7, c = idx & 127;
  float ah = 0.f, aw = 0.f;
  for (int m = 0; m < 128; ++m){
    ah += b2f(fh[o*128 + m]) * b2f(h1[m*128 + c]);
    aw += b2f(fw[o*128 + m]) * b2f(w1[m*128 + c]);
  }
  A_h[idx] = ah; A_w[idx] = aw;
  if (c == 0) biasK[o] = b2f(l1b[o]) + b2f(l2b[o]) + b2f(fcb[o]);
}

// ---------------- precompute: transposed f32 GEMM weights ----------------
__global__ void k_prep_T(const u16* __restrict__ qkv_w, const u16* __restrict__ pw_w,
                         float* __restrict__ At_qkv, float* __restrict__ At_pw){
  int idx = blockIdx.x * 256 + threadIdx.x;
  if (idx < 49152){ int r = idx >> 7, k = idx & 127; At_qkv[k*384 + r] = b2f(qkv_w[idx]); }
  else { int j = idx - 49152; int r = j >> 7, k = j & 127; At_pw[k*128 + r] = b2f(pw_w[j]); }
}

// ---------------- precompute: fused 13-tap kernel in bf16 [t][oc][ic] ----------------
__global__ void k_prep_K(const u16* __restrict__ hge_w, const u16* __restrict__ fc_w,
                         const u16* __restrict__ l1_w, const u16* __restrict__ l1_g,
                         const u16* __restrict__ l2_w, const u16* __restrict__ l2_g,
                         u16* __restrict__ Kwb){
  int idx = blockIdx.x * 256 + threadIdx.x;      // 16384, idx = o*128 + c
  int o = idx >> 7, c = idx & 127;
  float m0=0.f, m45=0.f, m90=0.f, m135=0.f, mgl=0.f;
  const u16* fo = fc_w + o*640;
  for (int m = 0; m < 128; ++m){
    const u16* hw9 = hge_w + (size_t)(m*128 + c)*9;
    m0   += b2f(fo[m      ]) * b2f(hw9[0]);
    m45  += b2f(fo[128 + m]) * b2f(hw9[1]);
    m90  += b2f(fo[256 + m]) * b2f(hw9[2]);
    m135 += b2f(fo[384 + m]) * b2f(hw9[3]);
    mgl  += b2f(fo[512 + m]) * b2f(hw9[8]);
  }
  float g1 = b2f(l1_g[o]) * RSQE;
  float g2 = b2f(l2_g[o]) * RSQE;
  float l1v[9];
  #pragma unroll
  for (int t = 0; t < 9; ++t) l1v[t] = b2f(l1_w[(size_t)idx*9 + t]) * g1;
  float l2v = b2f(l2_w[idx]) * g2;
  float kp[13];
  kp[0]  = -0.25f*mgl;
  kp[1]  =  m0 + 2.f*m45 + m90              - 0.25f*mgl + l1v[0];
  kp[2]  =  2.f*m0 + m45 - m135             - 0.50f*mgl + l1v[1];
  kp[3]  =  m0 - m90 - 2.f*m135             - 0.25f*mgl + l1v[2];
  kp[4]  = -0.25f*mgl;
  kp[5]  =  m45 + 2.f*m90 + m135            - 0.50f*mgl + l1v[3];
  kp[6]  =  4.f*mgl + l1v[4] + l2v;
  kp[7]  = -m45 - 2.f*m90 - m135            - 0.50f*mgl + l1v[5];
  kp[8]  = -0.25f*mgl;
  kp[9]  = -m0 + m90 + 2.f*m135             - 0.25f*mgl + l1v[6];
  kp[10] = -2.f*m0 - m45 + m135             - 0.50f*mgl + l1v[7];
  kp[11] = -m0 - 2.f*m45 - m90              - 0.25f*mgl + l1v[8];
  kp[12] = -0.25f*mgl;
  #pragma unroll
  for (int t = 0; t < 13; ++t) Kwb[t*16384 + idx] = f2b(kp[t]);
}

// ---------------- row/col means of x ----------------
__global__ void k_means(const u16* __restrict__ x, float* __restrict__ mh, float* __restrict__ mw){
  __shared__ float colpart[4][256];
  int c = blockIdx.x, b = blockIdx.y;
  const u16* xp = x + (size_t)(b*CC + c)*HWSZ;
  int tid = threadIdx.x, lane = tid & 63, wv = tid >> 6;
  float c0=0.f,c1=0.f,c2=0.f,c3=0.f;
  for (int r = 0; r < 64; ++r){
    int h = wv*64 + r;
    ushort4 u = *(const ushort4*)(xp + h*256 + lane*4);
    float v0=b2f(u.x), v1=b2f(u.y), v2=b2f(u.z), v3=b2f(u.w);
    c0+=v0; c1+=v1; c2+=v2; c3+=v3;
    float rs = v0+v1+v2+v3;
    #pragma unroll
    for (int off = 32; off > 0; off >>= 1) rs += __shfl_down(rs, off, 64);
    if (lane == 0) mh[(size_t)(b*CC + c)*256 + h] = rs * (1.0f/256.0f);
  }
  colpart[wv][lane*4+0]=c0; colpart[wv][lane*4+1]=c1;
  colpart[wv][lane*4+2]=c2; colpart[wv][lane*4+3]=c3;
  __syncthreads();
  mw[(size_t)(b*CC + c)*256 + tid] =
    (colpart[0][tid]+colpart[1][tid]+colpart[2][tid]+colpart[3][tid]) * (1.0f/256.0f);
}

// ---------------- sigmoid(A @ mean) ----------------
__global__ void k_sig(const float* __restrict__ A_h, const float* __restrict__ A_w,
                      const float* __restrict__ mh, const float* __restrict__ mw,
                      float* __restrict__ s_h, float* __restrict__ s_w){
  int o = blockIdx.x, b = blockIdx.y, sel = blockIdx.z, t = threadIdx.x;
  const float* A = sel ? A_w : A_h;
  const float* m = sel ? mw : mh;
  float* s = sel ? s_w : s_h;
  float acc = 0.f;
  for (int c = 0; c < 128; ++c)
    acc += A[o*128 + c] * m[(size_t)(b*CC + c)*256 + t];
  s[(size_t)(b*CC + o)*256 + t] = 1.0f / (1.0f + __expf(-acc));
}

// ---------------- xs = x * s_h * s_w ----------------
__global__ void k_scale(const u16* __restrict__ x, const float* __restrict__ s_h,
                        const float* __restrict__ s_w, u16* __restrict__ xs){
  int idx = blockIdx.x * 256 + threadIdx.x;
  int w4 = idx & 63; int h = (idx >> 6) & 255; int bc = idx >> 14;
  ushort4 u = ((const ushort4*)x)[idx];
  float sh = s_h[(size_t)bc*256 + h];
  float4 sw = ((const float4*)(s_w + (size_t)bc*256))[w4];
  ushort4 r;
  r.x = f2b(b2f(u.x)*sh*sw.x); r.y = f2b(b2f(u.y)*sh*sw.y);
  r.z = f2b(b2f(u.z)*sh*sw.z); r.w = f2b(b2f(u.w)*sh*sw.w);
  ((ushort4*)xs)[idx] = r;
}

// ---------------- channels-first -> channels-last padded [b][260][260][128] ----------------
__global__ void k_cf2cl(const u16* __restrict__ cx, u16* __restrict__ xcl){
  __shared__ u16 t[16][136];
  int b = blockIdx.z >> 8, h = blockIdx.z & 255;
  int w0 = blockIdx.x * 16;
  int tid = threadIdx.x;
  int ic = tid >> 1, wseg = (tid & 1) * 8;
  uint4 v = *(const uint4*)(cx + (size_t)(b*CC + ic)*HWSZ + h*256 + w0 + wseg);
  u16 tmp[8]; *(uint4*)tmp = v;
  #pragma unroll
  for (int k = 0; k < 8; ++k) t[wseg + k][ic] = tmp[k];
  __syncthreads();
  int w = tid >> 4, part = (tid & 15) * 8;
  uint4 o = *(const uint4*)&t[w][part];
  *(uint4*)(xcl + (((size_t)(b*260 + h + 2))*260 + (w0 + w + 2))*128 + part) = o;
}

// ---------------- MFMA implicit-GEMM conv ----------------
__launch_bounds__(256)
__global__ void k_conv5m(const u16* __restrict__ xcl, const u16* __restrict__ Kwb,
                         const float* __restrict__ biasK, u16* __restrict__ outp){
  __shared__ u16 As[128][40];
  __shared__ u16 Bs[128][40];
  int tid = threadIdx.x;
  int wv = tid >> 6, lane = tid & 63;
  int q = lane >> 4, l16 = lane & 15;
  int pt = blockIdx.x;
  int b = pt >> 9;
  int h = (pt >> 1) & 255;
  int w0 = (pt & 1) << 7;
  int mrow = (wv & 1) << 6;
  int nrow = (wv >> 1) << 6;
  int sr = tid >> 2, sp = (tid & 3) << 3;
  f32x4 acc[4][4];
  #pragma unroll
  for (int mt = 0; mt < 4; ++mt)
    #pragma unroll
    for (int nt = 0; nt < 4; ++nt) acc[mt][nt] = (f32x4){0.f,0.f,0.f,0.f};

  for (int kc = 0; kc < 52; ++kc){
    int t = kc >> 2, c0 = (kc & 3) << 5;
    int di = c_DI[t], dj = c_DJ[t];
    const u16* Ab = xcl + (((size_t)(b*260 + h + 2 + di))*260 + (w0 + 2 + dj))*128 + c0;
    const u16* Bb = Kwb + t*16384 + c0;
    __syncthreads();
    {
      uint4 va0 = *(const uint4*)(Ab + (size_t)sr*128 + sp);
      uint4 va1 = *(const uint4*)(Ab + (size_t)(sr + 64)*128 + sp);
      *(uint4*)&As[sr][sp] = va0;
      *(uint4*)&As[sr + 64][sp] = va1;
      uint4 vb0 = *(const uint4*)(Bb + sr*128 + sp);
      uint4 vb1 = *(const uint4*)(Bb + (sr + 64)*128 + sp);
      *(uint4*)&Bs[sr][sp] = vb0;
      *(uint4*)&Bs[sr + 64][sp] = vb1;
    }
    __syncthreads();
    short8 af[4], bf[4];
    #pragma unroll
    for (int mt = 0; mt < 4; ++mt) af[mt] = *(const short8*)&As[mrow + mt*16 + l16][q*8];
    #pragma unroll
    for (int nt = 0; nt < 4; ++nt) bf[nt] = *(const short8*)&Bs[nrow + nt*16 + l16][q*8];
    #pragma unroll
    for (int mt = 0; mt < 4; ++mt)
      #pragma unroll
      for (int nt = 0; nt < 4; ++nt)
        acc[mt][nt] = __builtin_amdgcn_mfma_f32_16x16x32_bf16(af[mt], bf[nt], acc[mt][nt], 0, 0, 0);
  }
  #pragma unroll
  for (int nt = 0; nt < 4; ++nt){
    int n = nrow + nt*16 + l16;
    float bv = biasK[n];
    size_t cbase = (size_t)(b*CC + n)*HWSZ + h*256 + w0;
    #pragma unroll
    for (int mt = 0; mt < 4; ++mt){
      int m = mrow + mt*16 + q*4;
      ushort4 st;
      st.x = f2b(acc[mt][nt][0] + bv);
      st.y = f2b(acc[mt][nt][1] + bv);
      st.z = f2b(acc[mt][nt][2] + bv);
      st.w = f2b(acc[mt][nt][3] + bv);
      *(ushort4*)(outp + cbase + m) = st;
    }
  }
}

// ---------------- tiled GEMM: Y = At^T(128xM) @ X[128][HW] ----------------
// wlayout=1: M=384 qkv -> window layout [b][hh][ww][sel][head][pos][d]
// wlayout=0: plane layout [b][M][HW]; f32 out if (Yf && *flag)
__launch_bounds__(256)
__global__ void k_gemm(const float* __restrict__ At, const u16* __restrict__ X,
                       u16* __restrict__ Y, float* __restrict__ Yf, int M,
                       const int* __restrict__ flag, int wlayout){
  __shared__ float As[4096], Xs[4096];
  int n0 = blockIdx.x * 64, m0 = blockIdx.y * 64, bz = blockIdx.z;
  const u16* Xb = X + (size_t)bz * 128 * HWSZ;
  int tid = threadIdx.x;
  int tn = tid & 15, tm = tid >> 4;
  float acc[4][4] = {};
  for (int kc = 0; kc < 128; kc += 64){
    __syncthreads();
    for (int e = tid; e < 4096; e += 256){
      int k = e >> 6, m = e & 63;
      As[e] = At[(size_t)(kc + k)*M + m0 + m];
    }
    for (int e = tid; e < 2048; e += 256){
      int k = e >> 5, j = (e & 31) * 2;
      unsigned int u = *(const unsigned int*)(Xb + (size_t)(kc + k)*HWSZ + n0 + j);
      float2 f; f.x = b2f((u16)(u & 0xffffu)); f.y = b2f((u16)(u >> 16));
      *(float2*)(Xs + k*64 + j) = f;
    }
    __syncthreads();
    #pragma unroll 8
    for (int k = 0; k < 64; ++k){
      float4 a  = *(const float4*)(As + k*64 + tm*4);
      float4 xv = *(const float4*)(Xs + k*64 + tn*4);
      acc[0][0] += a.x*xv.x; acc[0][1] += a.x*xv.y; acc[0][2] += a.x*xv.z; acc[0][3] += a.x*xv.w;
      acc[1][0] += a.y*xv.x; acc[1][1] += a.y*xv.y; acc[1][2] += a.y*xv.z; acc[1][3] += a.y*xv.w;
      acc[2][0] += a.z*xv.x; acc[2][1] += a.z*xv.y; acc[2][2] += a.z*xv.z; acc[2][3] += a.z*xv.w;
      acc[3][0] += a.w*xv.x; acc[3][1] += a.w*xv.y; acc[3][2] += a.w*xv.z; acc[3][3] += a.w*xv.w;
    }
  }
  if (wlayout){
    // ch = m0 + tm*4 + i ; pixel = n0 + tn*4 + j
    int sel = m0 >> 7;
    int cs = (m0 & 127) + tm*4;
    int head = cs >> 3, dsub = cs & 7;
    #pragma unroll
    for (int j = 0; j < 4; ++j){
      int p = n0 + tn*4 + j;
      int h = p >> 8, w = p & 255;
      int pos = (h & 7)*8 + (w & 7);
      size_t off = (((((size_t)bz*32 + (h>>3))*32 + (w>>3))*3 + sel)*16 + head)*512 + pos*8 + dsub;
      ushort4 st;
      st.x = f2b(acc[0][j]); st.y = f2b(acc[1][j]);
      st.z = f2b(acc[2][j]); st.w = f2b(acc[3][j]);
      *(ushort4*)(Y + off) = st;
    }
    return;
  }
  int f32o = (Yf != nullptr) && (*flag != 0);
  if (f32o){
    float* Yb = Yf + (size_t)bz * (size_t)M * HWSZ;
    #pragma unroll
    for (int i = 0; i < 4; ++i){
      float4 st; st.x=acc[i][0]; st.y=acc[i][1]; st.z=acc[i][2]; st.w=acc[i][3];
      *(float4*)(Yb + (size_t)(m0 + tm*4 + i)*HWSZ + n0 + tn*4) = st;
    }
  } else {
    u16* Yb = Y + (size_t)bz * (size_t)M * HWSZ;
    #pragma unroll
    for (int i = 0; i < 4; ++i){
      ushort4 st;
      st.x = f2b(acc[i][0]); st.y = f2b(acc[i][1]); st.z = f2b(acc[i][2]); st.w = f2b(acc[i][3]);
      *(ushort4*)(Yb + (size_t)(m0 + tm*4 + i)*HWSZ + n0 + tn*4) = st;
    }
  }
}

// ---------------- windowed attention v2: LDS-broadcast, no shuffles ----------------
// qkvw layout: [b][hh][ww][sel(3)][head(16)][pos(64)][d(8)] bf16
__launch_bounds__(128)
__global__ void k_attn2(const u16* __restrict__ qkvw, const u16* __restrict__ rel,
                        u16* __restrict__ obuf){
  __shared__ float relf[16*228];      // [head][225 pad 228]
  __shared__ u16  qls[2][64][8];      // bf16
  __shared__ u16  kls[2][64][8];      // bf16
  __shared__ float vls[2][64][8];     // f32
  __shared__ u16  ols[2][64][8];      // bf16 out
  int tid = threadIdx.x, wv = tid >> 6, lane = tid & 63;
  int b = blockIdx.z, hh = blockIdx.y, ww0 = blockIdx.x * 2;
  for (int e = tid; e < 3600; e += 128){
    int hd = e / 225, i = e - hd*225;
    relf[hd*228 + i] = b2f(rel[i*16 + hd]);
  }
  int qi = lane >> 3, qj = lane & 7;
  const float* rbase0 = relf + ((qi + 7)*15 + (qj + 7) - 112);
  size_t blkbase = (((size_t)b*32 + hh)*32 + ww0)*3*8192;  // + win*24576 + sel*8192 + head*512 + pos*8
  __syncthreads();

  for (int head = 0; head < 16; ++head){
    __syncthreads();
    // stage q,k: 256 segs of 16B (2 sel x 2 win x 64 pos), 2 per thread
    #pragma unroll
    for (int s = 0; s < 2; ++s){
      int seg = s*128 + tid;
      int sel = seg >> 7, win = (seg >> 6) & 1, pos = seg & 63;
      uint4 v = *(const uint4*)(qkvw + blkbase + (size_t)win*24576 + sel*8192 + head*512 + pos*8);
      if (sel == 0) *(uint4*)&qls[win][pos][0] = v;
      else          *(uint4*)&kls[win][pos][0] = v;
    }
    // stage v (f32): 128 segs, 1 per thread
    {
      int win = tid >> 6, pos = tid & 63;
      uint4 raw = *(const uint4*)(qkvw + blkbase + (size_t)win*24576 + 2*8192 + head*512 + pos*8);
      u16 tv[8]; *(uint4*)tv = raw;
      float4 lo, hi;
      lo.x=b2f(tv[0]); lo.y=b2f(tv[1]); lo.z=b2f(tv[2]); lo.w=b2f(tv[3]);
      hi.x=b2f(tv[4]); hi.y=b2f(tv[5]); hi.z=b2f(tv[6]); hi.w=b2f(tv[7]);
      *(float4*)&vls[win][pos][0] = lo;
      *(float4*)&vls[win][pos][4] = hi;
    }
    __syncthreads();

    // ---- compute: wave wv handles window wv ----
    uint4 qv = *(const uint4*)&qls[wv][lane][0];
    const float* rp = rbase0 + head*228;
    float s[64];
#if HAVE_DOT2
    typedef __bf16 bf2 __attribute__((ext_vector_type(2)));
    bf2 q0 = __builtin_bit_cast(bf2, qv.x), q1 = __builtin_bit_cast(bf2, qv.y);
    bf2 q2 = __builtin_bit_cast(bf2, qv.z), q3 = __builtin_bit_cast(bf2, qv.w);
    #pragma unroll
    for (int kp = 0; kp < 64; ++kp){
      uint4 kv = *(const uint4*)&kls[wv][kp][0];
      float d = __builtin_amdgcn_fdot2_f32_bf16(q3, __builtin_bit_cast(bf2, kv.w), 0.f, false);
      d = __builtin_amdgcn_fdot2_f32_bf16(q2, __builtin_bit_cast(bf2, kv.z), d, false);
      d = __builtin_amdgcn_fdot2_f32_bf16(q1, __builtin_bit_cast(bf2, kv.y), d, false);
      d = __builtin_amdgcn_fdot2_f32_bf16(q0, __builtin_bit_cast(bf2, kv.x), d, false);
      s[kp] = fmaf(d, ATT_SCALE, rp[112 - (kp>>3)*15 - (kp&7)]);
    }
#else
    float qf[8];
    { u16 tq[8]; *(uint4*)tq = qv;
      #pragma unroll
      for (int d = 0; d < 8; ++d) qf[d] = b2f(tq[d]); }
    #pragma unroll
    for (int kp = 0; kp < 64; ++kp){
      uint4 kv = *(const uint4*)&kls[wv][kp][0];
      u16 tk[8]; *(uint4*)tk = kv;
      float d = 0.f;
      #pragma unroll
      for (int dd = 0; dd < 8; ++dd) d = fmaf(qf[dd], b2f(tk[dd]), d);
      s[kp] = fmaf(d, ATT_SCALE, rp[112 - (kp>>3)*15 - (kp&7)]);
    }
#endif
    // softmax over 64
    float t16[16];
    #pragma unroll
    for (int i = 0; i < 16; ++i)
      t16[i] = fmaxf(fmaxf(s[i], s[i+16]), fmaxf(s[i+32], s[i+48]));
    float mx = t16[0];
    #pragma unroll
    for (int i = 1; i < 16; ++i) mx = fmaxf(mx, t16[i]);
    #pragma unroll
    for (int kp = 0; kp < 64; ++kp) s[kp] = __expf(s[kp] - mx);
    #pragma unroll
    for (int i = 0; i < 16; ++i)
      t16[i] = (s[i] + s[i+16]) + (s[i+32] + s[i+48]);
    float sum = t16[0];
    #pragma unroll
    for (int i = 1; i < 16; ++i) sum += t16[i];
    float inv = 1.0f / sum;
    // PV
    float ov[8] = {0.f,0.f,0.f,0.f,0.f,0.f,0.f,0.f};
    #pragma unroll
    for (int kp = 0; kp < 64; ++kp){
      float4 va = *(const float4*)&vls[wv][kp][0];
      float4 vb = *(const float4*)&vls[wv][kp][4];
      float pp = s[kp];
      ov[0] = fmaf(pp, va.x, ov[0]); ov[1] = fmaf(pp, va.y, ov[1]);
      ov[2] = fmaf(pp, va.z, ov[2]); ov[3] = fmaf(pp, va.w, ov[3]);
      ov[4] = fmaf(pp, vb.x, ov[4]); ov[5] = fmaf(pp, vb.y, ov[5]);
      ov[6] = fmaf(pp, vb.z, ov[6]); ov[7] = fmaf(pp, vb.w, ov[7]);
    }
    u16 po[8];
    #pragma unroll
    for (int d = 0; d < 8; ++d) po[d] = f2b(ov[d] * inv);
    *(uint4*)&ols[wv][lane][0] = *(uint4*)po;
    __syncthreads();
    // transpose-out to plane layout: 128 segs (2 win x 8 d x 8 r)
    {
      int win = tid >> 6, d = (tid >> 3) & 7, r = tid & 7;
      u16 pk[8];
      #pragma unroll
      for (int wl = 0; wl < 8; ++wl) pk[wl] = ols[win][r*8 + wl][d];
      *(uint4*)(obuf + (size_t)(b*CC + head*8 + d)*HWSZ + (hh*8 + r)*256 + (ww0 + win)*8)
        = *(uint4*)pk;
    }
  }
}

// ---------------- u = avgpool_x(o) + avgpool_y(o) + local ----------------
__global__ void k_pool(const u16* __restrict__ obuf, u16* __restrict__ localb){
  int idx = blockIdx.x * 256 + threadIdx.x;
  int w = idx & 255, h = (idx >> 8) & 255; int bc = idx >> 16;
  const u16* oc_ = obuf + (size_t)bc * HWSZ;
  float sx = 0.f;
  #pragma unroll
  for (int u = 0; u < 8; ++u){
    int t = h - 3 + u;
    if (t == 256) t = 254;
    if ((unsigned)t <= 255u) sx += b2f(oc_[t*256 + w]);
  }
  float sy = 0.f;
  #pragma unroll
  for (int u = 0; u < 8; ++u){
    int t = w - 3 + u;
    if (t == 256) t = 254;
    if ((unsigned)t <= 255u) sy += b2f(oc_[h*256 + t]);
  }
  float res = (sx + sy) * 0.125f + b2f(localb[idx]);
  localb[idx] = f2b(res);
}

// ---------------- depthwise 8x8 conv + bn ----------------
__launch_bounds__(256)
__global__ void k_dw(const u16* __restrict__ u_, const u16* __restrict__ dww,
                     const u16* __restrict__ g, const u16* __restrict__ bta,
                     u16* __restrict__ dwout){
  __shared__ float xt[23][24];
  __shared__ float wt[64];
  int c = blockIdx.z & 127, b = blockIdx.z >> 7;
  int h0 = blockIdx.y*16, w0 = blockIdx.x*16;
  int tid = threadIdx.x;
  const u16* up = u_ + (size_t)(b*CC + c)*HWSZ;
  for (int e = tid; e < 529; e += 256){
    int r = e / 23, q = e - r*23;
    int ih = h0 - 3 + r, iw = w0 - 3 + q;
    if (ih == 256) ih = 254;
    if (iw == 256) iw = 254;
    float v = 0.f;
    if ((unsigned)ih <= 255u && (unsigned)iw <= 255u) v = b2f(up[ih*256 + iw]);
    xt[r][q] = v;
  }
  if (tid < 64) wt[tid] = b2f(dww[c*64 + tid]);
  __syncthreads();
  int py = tid >> 4, px = tid & 15;
  float acc = 0.f;
  #pragma unroll
  for (int i = 0; i < 8; ++i)
    #pragma unroll
    for (int j = 0; j < 8; ++j)
      acc += wt[i*8+j] * xt[py+i][px+j];
  float scale = b2f(g[c]) * RSQE;
  dwout[(size_t)(b*CC + c)*HWSZ + (h0+py)*256 + (w0+px)] = f2b(acc*scale + b2f(bta[c]));
}

// ---------------- launcher ----------------
extern "C" void kernel_launch(void* const* d_in, const int* in_sizes, int n_in,
                              void* d_out, int out_size, void* d_ws, size_t ws_size,
                              hipStream_t stream) {
  char* p = (char*)d_ws;
  u16* cx     = (u16*)p; p += 33554432;   // canonical x -> scaled x -> attn output planes
  u16* qkvb   = (u16*)p; p += 100663296;  // xcl -> qkvw (window layout) -> dw output
  u16* cw     = (u16*)p; p += 1074176;
  float* At_qkv = (float*)p; p += 196608;
  float* At_pw  = (float*)p; p += 65536;
  float* A_h    = (float*)p; p += 65536;
  float* A_w    = (float*)p; p += 65536;
  u16*  Kwb     = (u16*)p;  p += 425984;
  float* biasK  = (float*)p; p += 1024;
  float* mh     = (float*)p; p += 262144;
  float* mw     = (float*)p; p += 262144;
  float* s_h    = (float*)p; p += 262144;
  float* s_w    = (float*)p; p += 262144;
  int* flag     = (int*)p;   p += 256;

  u16* localb = (u16*)d_out;
  u16* xcl    = qkvb;
  u16* qkvw   = qkvb;
  u16* obuf   = cx;
  u16* dwbuf  = qkvb;

  const int O_h1=0, O_w1=16384, O_fh=32768, O_fw=49152, O_l1w=65536, O_l1g=212992,
            O_l1b=213120, O_l2w=213248, O_l2g=229632, O_l2b=229760, O_hge=229888,
            O_fcw=377344, O_fcb=459264, O_qkvw=459392, O_rel=508544, O_dw=512144,
            O_pg=520336, O_pb=520464, O_pw=520592;

  k_detect<<<1, 256, 0, stream>>>((const u16*)d_in[0], flag);
  k_ingest4<<<16384, 256, 0, stream>>>(d_in[0], cx, 4194304, flag);
  PtrL pl;
  for (int i = 0; i < 19; ++i) pl.p[i] = d_in[i+1];
  k_ingest_w<<<525, 256, 0, stream>>>(pl, cw, flag);

  k_prep_A<<<64, 256, 0, stream>>>(cw+O_fh, cw+O_h1, cw+O_fw, cw+O_w1,
                                   cw+O_l1b, cw+O_l2b, cw+O_fcb, A_h, A_w, biasK);
  k_prep_T<<<256, 256, 0, stream>>>(cw+O_qkvw, cw+O_pw, At_qkv, At_pw);
  k_prep_K<<<64, 256, 0, stream>>>(cw+O_hge, cw+O_fcw, cw+O_l1w, cw+O_l1g,
                                   cw+O_l2w, cw+O_l2g, Kwb);
  k_means<<<dim3(128, 2), 256, 0, stream>>>(cx, mh, mw);
  k_sig<<<dim3(128, 2, 2), 256, 0, stream>>>(A_h, A_w, mh, mw, s_h, s_w);
  k_scale<<<16384, 256, 0, stream>>>(cx, s_h, s_w, cx);

  hipMemsetAsync(xcl, 0, (size_t)2*260*260*128*2, stream);
  k_cf2cl<<<dim3(16, 1, 512), 256, 0, stream>>>(cx, xcl);
  k_conv5m<<<1024, 256, 0, stream>>>(xcl, Kwb, biasK, localb);

  k_gemm<<<dim3(1024, 6, 2), 256, 0, stream>>>(At_qkv, cx, qkvw, nullptr, 384, flag, 1);
  k_attn2<<<dim3(16, 32, 2), 128, 0, stream>>>(qkvw, cw+O_rel, obuf);
  k_pool<<<65536, 256, 0, stream>>>(obuf, localb);
  k_dw<<<dim3(16, 16, 256), 256, 0, stream>>>(localb, cw+O_dw, cw+O_pg, cw+O_pb, dwbuf);
  k_gemm<<<dim3(1024, 2, 2), 256, 0, stream>>>(At_pw, dwbuf, (u16*)d_out, (float*)d_out, 128, flag, 0);
}

// Round 5
// 869.418 us; speedup vs baseline: 4.2476x; 1.1839x over previous
//
#include <hip/hip_runtime.h>

// x: (B=2, C=128, H=256, W=256); WS=8, NH=16, d=8
#define BB 2
#define CC 128
#define HWSZ 65536
#define RSQE 0.9999950000374997f   // 1/sqrt(1+1e-5)
#define ATT_SCALE 0.35355339059327373f

typedef unsigned short u16;
using short8 = __attribute__((ext_vector_type(8))) short;
using f32x4  = __attribute__((ext_vector_type(4))) float;

#if defined(__has_builtin)
# if __has_builtin(__builtin_amdgcn_fdot2_f32_bf16)
#  define HAVE_DOT2 1
# endif
#endif

__device__ __forceinline__ float b2f(u16 u){
  return __uint_as_float(((unsigned int)u) << 16);
}
__device__ __forceinline__ u16 f2b(float f){
  unsigned int v = __float_as_uint(f);
  unsigned int r = (v + 0x7FFFu + ((v >> 16) & 1u)) >> 16;
  return (u16)r;
}

// tap offsets for the fused 13-tap 5x5 kernel (order matches k_prep_K)
__device__ const int c_DI[13] = {-2,-1,-1,-1, 0, 0,0,0,0, 1,1,1, 2};
__device__ const int c_DJ[13] = { 0,-1, 0, 1,-2,-1,0,1,2,-1,0,1, 0};

// ---------------- dtype detection ----------------
__global__ void k_detect(const u16* __restrict__ xr, int* __restrict__ flag){
  __shared__ int ws_[4];
  int tid = threadIdx.x;
  int cnt = 0;
  for (int i = 0; i < 16; ++i){
    u16 u = xr[tid*16 + i];
    int e = (u >> 7) & 0xFF;
    cnt += (e < 100 || e > 141) ? 1 : 0;
  }
  #pragma unroll
  for (int off = 32; off > 0; off >>= 1) cnt += __shfl_down(cnt, off, 64);
  if ((tid & 63) == 0) ws_[tid >> 6] = cnt;
  __syncthreads();
  if (tid == 0) *flag = (ws_[0]+ws_[1]+ws_[2]+ws_[3] > 64) ? 1 : 0;
}

// ---------------- ingest ----------------
__global__ void k_ingest4(const void* __restrict__ src, u16* __restrict__ dst,
                          int n4, const int* __restrict__ flag){
  int i = blockIdx.x * 256 + threadIdx.x;
  if (i >= n4) return;
  if (*flag){
    float4 f = ((const float4*)src)[i];
    ushort4 r; r.x=f2b(f.x); r.y=f2b(f.y); r.z=f2b(f.z); r.w=f2b(f.w);
    ((ushort4*)dst)[i] = r;
  } else {
    ((ushort4*)dst)[i] = ((const ushort4*)src)[i];
  }
}

struct PtrL { const void* p[19]; };

__global__ void k_ingest_w(PtrL pl, u16* __restrict__ dst, const int* __restrict__ flag){
  const int ends[19] = {16384,32768,49152,65536,212992,213120,213248,229632,229760,
                        229888,377344,459264,459392,508544,512144,520336,520464,520592,536976};
  int g = blockIdx.x * 256 + threadIdx.x;
  int idx = g * 4;
  if (idx >= 536976) return;
  int seg = 0, start = 0;
  #pragma unroll
  for (int s = 0; s < 19; ++s){ if (idx >= ends[s]){ seg = s+1; start = ends[s]; } }
  int local = idx - start;
  const void* sp = pl.p[seg];
  if (*flag){
    float4 f = ((const float4*)sp)[local >> 2];
    ushort4 r; r.x=f2b(f.x); r.y=f2b(f.y); r.z=f2b(f.z); r.w=f2b(f.w);
    *(ushort4*)(dst + idx) = r;
  } else {
    *(ushort4*)(dst + idx) = ((const ushort4*)sp)[local >> 2];
  }
}

// ---------------- precompute: channel-attention matrices + combined bias ----------------
__global__ void k_prep_A(const u16* __restrict__ fh, const u16* __restrict__ h1,
                         const u16* __restrict__ fw, const u16* __restrict__ w1,
                         const u16* __restrict__ l1b, const u16* __restrict__ l2b,
                         const u16* __restrict__ fcb,
                         float* __restrict__ A_h, float* __restrict__ A_w,
                         float* __restrict__ biasK){
  int idx = blockIdx.x * 256 + threadIdx.x;
  int o = idx >> 7, c = idx & 127;
  float ah = 0.f, aw = 0.f;
  for (int m = 0; m < 128; ++m){
    ah += b2f(fh[o*128 + m]) * b2f(h1[m*128 + c]);
    aw += b2f(fw[o*128 + m]) * b2f(w1[m*128 + c]);
  }
  A_h[idx] = ah; A_w[idx] = aw;
  if (c == 0) biasK[o] = b2f(l1b[o]) + b2f(l2b[o]) + b2f(fcb[o]);
}

// ---------------- precompute: fused 13-tap kernel in bf16 [t][oc][ic] ----------------
__global__ void k_prep_K(const u16* __restrict__ hge_w, const u16* __restrict__ fc_w,
                         const u16* __restrict__ l1_w, const u16* __restrict__ l1_g,
                         const u16* __restrict__ l2_w, const u16* __restrict__ l2_g,
                         u16* __restrict__ Kwb){
  int idx = blockIdx.x * 256 + threadIdx.x;      // 16384, idx = o*128 + c
  int o = idx >> 7, c = idx & 127;
  float m0=0.f, m45=0.f, m90=0.f, m135=0.f, mgl=0.f;
  const u16* fo = fc_w + o*640;
  for (int m = 0; m < 128; ++m){
    const u16* hw9 = hge_w + (size_t)(m*128 + c)*9;
    m0   += b2f(fo[m      ]) * b2f(hw9[0]);
    m45  += b2f(fo[128 + m]) * b2f(hw9[1]);
    m90  += b2f(fo[256 + m]) * b2f(hw9[2]);
    m135 += b2f(fo[384 + m]) * b2f(hw9[3]);
    mgl  += b2f(fo[512 + m]) * b2f(hw9[8]);
  }
  float g1 = b2f(l1_g[o]) * RSQE;
  float g2 = b2f(l2_g[o]) * RSQE;
  float l1v[9];
  #pragma unroll
  for (int t = 0; t < 9; ++t) l1v[t] = b2f(l1_w[(size_t)idx*9 + t]) * g1;
  float l2v = b2f(l2_w[idx]) * g2;
  float kp[13];
  kp[0]  = -0.25f*mgl;
  kp[1]  =  m0 + 2.f*m45 + m90              - 0.25f*mgl + l1v[0];
  kp[2]  =  2.f*m0 + m45 - m135             - 0.50f*mgl + l1v[1];
  kp[3]  =  m0 - m90 - 2.f*m135             - 0.25f*mgl + l1v[2];
  kp[4]  = -0.25f*mgl;
  kp[5]  =  m45 + 2.f*m90 + m135            - 0.50f*mgl + l1v[3];
  kp[6]  =  4.f*mgl + l1v[4] + l2v;
  kp[7]  = -m45 - 2.f*m90 - m135            - 0.50f*mgl + l1v[5];
  kp[8]  = -0.25f*mgl;
  kp[9]  = -m0 + m90 + 2.f*m135             - 0.25f*mgl + l1v[6];
  kp[10] = -2.f*m0 - m45 + m135             - 0.50f*mgl + l1v[7];
  kp[11] = -m0 - 2.f*m45 - m90              - 0.25f*mgl + l1v[8];
  kp[12] = -0.25f*mgl;
  #pragma unroll
  for (int t = 0; t < 13; ++t) Kwb[t*16384 + idx] = f2b(kp[t]);
}

// ---------------- row/col means of x (canonical, pre-scale) ----------------
__global__ void k_means(const u16* __restrict__ x, float* __restrict__ mh, float* __restrict__ mw){
  __shared__ float colpart[4][256];
  int c = blockIdx.x, b = blockIdx.y;
  const u16* xp = x + (size_t)(b*CC + c)*HWSZ;
  int tid = threadIdx.x, lane = tid & 63, wv = tid >> 6;
  float c0=0.f,c1=0.f,c2=0.f,c3=0.f;
  for (int r = 0; r < 64; ++r){
    int h = wv*64 + r;
    ushort4 u = *(const ushort4*)(xp + h*256 + lane*4);
    float v0=b2f(u.x), v1=b2f(u.y), v2=b2f(u.z), v3=b2f(u.w);
    c0+=v0; c1+=v1; c2+=v2; c3+=v3;
    float rs = v0+v1+v2+v3;
    #pragma unroll
    for (int off = 32; off > 0; off >>= 1) rs += __shfl_down(rs, off, 64);
    if (lane == 0) mh[(size_t)(b*CC + c)*256 + h] = rs * (1.0f/256.0f);
  }
  colpart[wv][lane*4+0]=c0; colpart[wv][lane*4+1]=c1;
  colpart[wv][lane*4+2]=c2; colpart[wv][lane*4+3]=c3;
  __syncthreads();
  mw[(size_t)(b*CC + c)*256 + tid] =
    (colpart[0][tid]+colpart[1][tid]+colpart[2][tid]+colpart[3][tid]) * (1.0f/256.0f);
}

// ---------------- sigmoid(A @ mean) ----------------
__global__ void k_sig(const float* __restrict__ A_h, const float* __restrict__ A_w,
                      const float* __restrict__ mh, const float* __restrict__ mw,
                      float* __restrict__ s_h, float* __restrict__ s_w){
  int o = blockIdx.x, b = blockIdx.y, sel = blockIdx.z, t = threadIdx.x;
  const float* A = sel ? A_w : A_h;
  const float* m = sel ? mw : mh;
  float* s = sel ? s_w : s_h;
  float acc = 0.f;
  for (int c = 0; c < 128; ++c)
    acc += A[o*128 + c] * m[(size_t)(b*CC + c)*256 + t];
  s[(size_t)(b*CC + o)*256 + t] = 1.0f / (1.0f + __expf(-acc));
}

// ---------------- fused scale + CF->CL: xcl[b][h][w][c] = x*s_h*s_w ----------------
__global__ void k_scale2cl(const u16* __restrict__ cx, const float* __restrict__ s_h,
                           const float* __restrict__ s_w, u16* __restrict__ xcl){
  __shared__ u16 t[16][136];
  int b = blockIdx.z >> 8, h = blockIdx.z & 255;
  int w0 = blockIdx.x * 16;
  int tid = threadIdx.x;
  int ic = tid >> 1, wseg = (tid & 1) * 8;
  uint4 v = *(const uint4*)(cx + (size_t)(b*CC + ic)*HWSZ + h*256 + w0 + wseg);
  float sh = s_h[(size_t)(b*CC + ic)*256 + h];
  const float* swp = s_w + (size_t)(b*CC + ic)*256 + w0 + wseg;
  float4 swa = *(const float4*)swp;
  float4 swb = *(const float4*)(swp + 4);
  u16 tmp[8]; *(uint4*)tmp = v;
  t[wseg+0][ic] = f2b(b2f(tmp[0])*sh*swa.x);
  t[wseg+1][ic] = f2b(b2f(tmp[1])*sh*swa.y);
  t[wseg+2][ic] = f2b(b2f(tmp[2])*sh*swa.z);
  t[wseg+3][ic] = f2b(b2f(tmp[3])*sh*swa.w);
  t[wseg+4][ic] = f2b(b2f(tmp[4])*sh*swb.x);
  t[wseg+5][ic] = f2b(b2f(tmp[5])*sh*swb.y);
  t[wseg+6][ic] = f2b(b2f(tmp[6])*sh*swb.z);
  t[wseg+7][ic] = f2b(b2f(tmp[7])*sh*swb.w);
  __syncthreads();
  int w = tid >> 4, part = (tid & 15) * 8;
  uint4 o = *(const uint4*)&t[w][part];
  *(uint4*)(xcl + ((size_t)(b*256 + h)*256 + (w0 + w))*128 + part) = o;
}

// ---------------- plain CF -> CL transpose ----------------
__global__ void k_cf2cl(const u16* __restrict__ src, u16* __restrict__ dst){
  __shared__ u16 t[16][136];
  int b = blockIdx.z >> 8, h = blockIdx.z & 255;
  int w0 = blockIdx.x * 16;
  int tid = threadIdx.x;
  int ic = tid >> 1, wseg = (tid & 1) * 8;
  uint4 v = *(const uint4*)(src + (size_t)(b*CC + ic)*HWSZ + h*256 + w0 + wseg);
  u16 tmp[8]; *(uint4*)tmp = v;
  #pragma unroll
  for (int k = 0; k < 8; ++k) t[wseg + k][ic] = tmp[k];
  __syncthreads();
  int w = tid >> 4, part = (tid & 15) * 8;
  uint4 o = *(const uint4*)&t[w][part];
  *(uint4*)(dst + ((size_t)(b*256 + h)*256 + (w0 + w))*128 + part) = o;
}

// ---------------- MFMA implicit-GEMM conv (unpadded CL input, masked halo) ----------------
__launch_bounds__(256)
__global__ void k_conv5m(const u16* __restrict__ xcl, const u16* __restrict__ Kwb,
                         const float* __restrict__ biasK, u16* __restrict__ outp){
  __shared__ u16 As[128][40];
  __shared__ u16 Bs[128][40];
  int tid = threadIdx.x;
  int wv = tid >> 6, lane = tid & 63;
  int q = lane >> 4, l16 = lane & 15;
  int pt = blockIdx.x;
  int b = pt >> 9, h = (pt >> 1) & 255, w0 = (pt & 1) << 7;
  int mrow = (wv & 1) << 6, nrow = (wv >> 1) << 6;
  int sr = tid >> 2, sp = (tid & 3) << 3;
  const u16* xb_b = xcl + (size_t)b*HWSZ*128;
  f32x4 acc[4][4];
  #pragma unroll
  for (int mt = 0; mt < 4; ++mt)
    #pragma unroll
    for (int nt = 0; nt < 4; ++nt) acc[mt][nt] = (f32x4){0.f,0.f,0.f,0.f};

  for (int kc = 0; kc < 52; ++kc){
    int t = kc >> 2, c0 = (kc & 3) << 5;
    int di = c_DI[t], dj = c_DJ[t];
    int hh2 = h + di;
    bool rowok = (unsigned)hh2 < 256u;
    const u16* rowp = xb_b + (size_t)(rowok ? hh2 : 0)*256*128 + c0 + sp;
    int col0 = w0 + dj + sr;
    int col1 = col0 + 64;
    __syncthreads();
    {
      uint4 va0 = {0,0,0,0}, va1 = {0,0,0,0};
      if (rowok && (unsigned)col0 < 256u) va0 = *(const uint4*)(rowp + col0*128);
      if (rowok && (unsigned)col1 < 256u) va1 = *(const uint4*)(rowp + col1*128);
      *(uint4*)&As[sr][sp] = va0;
      *(uint4*)&As[sr + 64][sp] = va1;
      const u16* Bb = Kwb + t*16384 + c0;
      *(uint4*)&Bs[sr][sp] = *(const uint4*)(Bb + sr*128 + sp);
      *(uint4*)&Bs[sr + 64][sp] = *(const uint4*)(Bb + (sr + 64)*128 + sp);
    }
    __syncthreads();
    short8 af[4], bf[4];
    #pragma unroll
    for (int mt = 0; mt < 4; ++mt) af[mt] = *(const short8*)&As[mrow + mt*16 + l16][q*8];
    #pragma unroll
    for (int nt = 0; nt < 4; ++nt) bf[nt] = *(const short8*)&Bs[nrow + nt*16 + l16][q*8];
    #pragma unroll
    for (int mt = 0; mt < 4; ++mt)
      #pragma unroll
      for (int nt = 0; nt < 4; ++nt)
        acc[mt][nt] = __builtin_amdgcn_mfma_f32_16x16x32_bf16(af[mt], bf[nt], acc[mt][nt], 0, 0, 0);
  }
  #pragma unroll
  for (int nt = 0; nt < 4; ++nt){
    int n = nrow + nt*16 + l16;
    float bv = biasK[n];
    size_t cbase = (size_t)(b*CC + n)*HWSZ + h*256 + w0;
    #pragma unroll
    for (int mt = 0; mt < 4; ++mt){
      int m = mrow + mt*16 + q*4;
      ushort4 st;
      st.x = f2b(acc[mt][nt][0] + bv);
      st.y = f2b(acc[mt][nt][1] + bv);
      st.z = f2b(acc[mt][nt][2] + bv);
      st.w = f2b(acc[mt][nt][3] + bv);
      *(ushort4*)(outp + cbase + m) = st;
    }
  }
}

// ---------------- MFMA 1x1 GEMM: out[px][oc] = X_cl[px][:]·W[oc][:] ----------------
// mode 0: window layout [b][hh][ww][sel][head][pos][d] (qkv, nsel=3)
// mode 1: plane CF [b][oc][HW]; f32 if (Yf && *flag)   (proj_pw, nsel=1)
__launch_bounds__(256)
__global__ void k_mgemm(const u16* __restrict__ Xcl, const u16* __restrict__ W,
                        u16* __restrict__ Y, float* __restrict__ Yf,
                        const int* __restrict__ flag, int nsel, int mode){
  __shared__ u16 As[128][136];
  __shared__ u16 Bs[128][136];   // reused as Cs[m][n] in mode-0 epilogue
  int tid = threadIdx.x;
  int wv = tid >> 6, lane = tid & 63;
  int q = lane >> 4, l16 = lane & 15;
  int pt = blockIdx.x;
  int b = pt >> 9, h = (pt >> 1) & 255, w0 = (pt & 1) << 7;
  int mrow = (wv & 1) << 6, nrow = (wv >> 1) << 6;
  const u16* Abase = Xcl + ((size_t)(b*256 + h)*256 + w0)*128;
  #pragma unroll
  for (int i = 0; i < 8; ++i){
    int seg = i*256 + tid;
    *(uint4*)&As[seg >> 4][(seg & 15) << 3] = *(const uint4*)(Abase + seg*8);
  }
  for (int sel = 0; sel < nsel; ++sel){
    __syncthreads();                  // Bs/Cs free of previous readers
    const u16* Wb = W + sel*16384;
    #pragma unroll
    for (int i = 0; i < 8; ++i){
      int seg = i*256 + tid;
      *(uint4*)&Bs[seg >> 4][(seg & 15) << 3] = *(const uint4*)(Wb + seg*8);
    }
    __syncthreads();
    f32x4 acc[4][4];
    #pragma unroll
    for (int mt = 0; mt < 4; ++mt)
      #pragma unroll
      for (int nt = 0; nt < 4; ++nt) acc[mt][nt] = (f32x4){0.f,0.f,0.f,0.f};
    #pragma unroll
    for (int kc = 0; kc < 4; ++kc){
      short8 af[4], bf[4];
      #pragma unroll
      for (int mt = 0; mt < 4; ++mt) af[mt] = *(const short8*)&As[mrow + mt*16 + l16][kc*32 + q*8];
      #pragma unroll
      for (int nt = 0; nt < 4; ++nt) bf[nt] = *(const short8*)&Bs[nrow + nt*16 + l16][kc*32 + q*8];
      #pragma unroll
      for (int mt = 0; mt < 4; ++mt)
        #pragma unroll
        for (int nt = 0; nt < 4; ++nt)
          acc[mt][nt] = __builtin_amdgcn_mfma_f32_16x16x32_bf16(af[mt], bf[nt], acc[mt][nt], 0, 0, 0);
    }
    if (mode == 0){
      __syncthreads();                // all waves done with Bs
      #pragma unroll
      for (int mt = 0; mt < 4; ++mt){
        int m0i = mrow + mt*16 + q*4;
        #pragma unroll
        for (int nt = 0; nt < 4; ++nt){
          int n = nrow + nt*16 + l16;
          Bs[m0i+0][n] = f2b(acc[mt][nt][0]);
          Bs[m0i+1][n] = f2b(acc[mt][nt][1]);
          Bs[m0i+2][n] = f2b(acc[mt][nt][2]);
          Bs[m0i+3][n] = f2b(acc[mt][nt][3]);
        }
      }
      __syncthreads();
      int win = tid >> 4, head = tid & 15;
      size_t obase = (((((size_t)b*32 + (h >> 3))*32 + (w0 >> 3) + win)*3 + sel)*16 + head)*512
                     + (size_t)(h & 7)*64;
      #pragma unroll
      for (int pj = 0; pj < 8; ++pj){
        uint4 vv = *(const uint4*)&Bs[win*8 + pj][head*8];
        *(uint4*)(Y + obase + pj*8) = vv;
      }
    } else {
      int f32o = (Yf != nullptr) && (*flag != 0);
      #pragma unroll
      for (int nt = 0; nt < 4; ++nt){
        int n = nrow + nt*16 + l16;
        size_t cbase = (size_t)(b*CC + n)*HWSZ + h*256 + w0;
        #pragma unroll
        for (int mt = 0; mt < 4; ++mt){
          int m = mrow + mt*16 + q*4;
          if (f32o){
            float4 st; st.x=acc[mt][nt][0]; st.y=acc[mt][nt][1];
            st.z=acc[mt][nt][2]; st.w=acc[mt][nt][3];
            *(float4*)(Yf + cbase + m) = st;
          } else {
            ushort4 st;
            st.x = f2b(acc[mt][nt][0]); st.y = f2b(acc[mt][nt][1]);
            st.z = f2b(acc[mt][nt][2]); st.w = f2b(acc[mt][nt][3]);
            *(ushort4*)(Y + cbase + m) = st;
          }
        }
      }
    }
  }
}

// ---------------- windowed attention v2 ----------------
// qkvw layout: [b][hh][ww][sel(3)][head(16)][pos(64)][d(8)] bf16
__launch_bounds__(128)
__global__ void k_attn2(const u16* __restrict__ qkvw, const u16* __restrict__ rel,
                        u16* __restrict__ obuf){
  __shared__ float relf[16*228];
  __shared__ u16  qls[2][64][8];
  __shared__ u16  kls[2][64][8];
  __shared__ float vls[2][64][8];
  __shared__ u16  ols[2][64][8];
  int tid = threadIdx.x, wv = tid >> 6, lane = tid & 63;
  int b = blockIdx.z, hh = blockIdx.y, ww0 = blockIdx.x * 2;
  for (int e = tid; e < 3600; e += 128){
    int hd = e / 225, i = e - hd*225;
    relf[hd*228 + i] = b2f(rel[i*16 + hd]);
  }
  int qi = lane >> 3, qj = lane & 7;
  const float* rbase0 = relf + ((qi + 7)*15 + (qj + 7) - 112);
  size_t blkbase = (((size_t)b*32 + hh)*32 + ww0)*3*8192;
  __syncthreads();

  for (int head = 0; head < 16; ++head){
    __syncthreads();
    #pragma unroll
    for (int s = 0; s < 2; ++s){
      int seg = s*128 + tid;
      int sel = seg >> 7, win = (seg >> 6) & 1, pos = seg & 63;
      uint4 v = *(const uint4*)(qkvw + blkbase + (size_t)win*24576 + sel*8192 + head*512 + pos*8);
      if (sel == 0) *(uint4*)&qls[win][pos][0] = v;
      else          *(uint4*)&kls[win][pos][0] = v;
    }
    {
      int win = tid >> 6, pos = tid & 63;
      uint4 raw = *(const uint4*)(qkvw + blkbase + (size_t)win*24576 + 2*8192 + head*512 + pos*8);
      u16 tv[8]; *(uint4*)tv = raw;
      float4 lo, hi;
      lo.x=b2f(tv[0]); lo.y=b2f(tv[1]); lo.z=b2f(tv[2]); lo.w=b2f(tv[3]);
      hi.x=b2f(tv[4]); hi.y=b2f(tv[5]); hi.z=b2f(tv[6]); hi.w=b2f(tv[7]);
      *(float4*)&vls[win][pos][0] = lo;
      *(float4*)&vls[win][pos][4] = hi;
    }
    __syncthreads();

    uint4 qv = *(const uint4*)&qls[wv][lane][0];
    const float* rp = rbase0 + head*228;
    float s[64];
#if HAVE_DOT2
    typedef __bf16 bf2 __attribute__((ext_vector_type(2)));
    bf2 q0 = __builtin_bit_cast(bf2, qv.x), q1 = __builtin_bit_cast(bf2, qv.y);
    bf2 q2 = __builtin_bit_cast(bf2, qv.z), q3 = __builtin_bit_cast(bf2, qv.w);
    #pragma unroll
    for (int kp = 0; kp < 64; ++kp){
      uint4 kv = *(const uint4*)&kls[wv][kp][0];
      float d = __builtin_amdgcn_fdot2_f32_bf16(q3, __builtin_bit_cast(bf2, kv.w), 0.f, false);
      d = __builtin_amdgcn_fdot2_f32_bf16(q2, __builtin_bit_cast(bf2, kv.z), d, false);
      d = __builtin_amdgcn_fdot2_f32_bf16(q1, __builtin_bit_cast(bf2, kv.y), d, false);
      d = __builtin_amdgcn_fdot2_f32_bf16(q0, __builtin_bit_cast(bf2, kv.x), d, false);
      s[kp] = fmaf(d, ATT_SCALE, rp[112 - (kp>>3)*15 - (kp&7)]);
    }
#else
    float qf[8];
    { u16 tq[8]; *(uint4*)tq = qv;
      #pragma unroll
      for (int d = 0; d < 8; ++d) qf[d] = b2f(tq[d]); }
    #pragma unroll
    for (int kp = 0; kp < 64; ++kp){
      uint4 kv = *(const uint4*)&kls[wv][kp][0];
      u16 tk[8]; *(uint4*)tk = kv;
      float d = 0.f;
      #pragma unroll
      for (int dd = 0; dd < 8; ++dd) d = fmaf(qf[dd], b2f(tk[dd]), d);
      s[kp] = fmaf(d, ATT_SCALE, rp[112 - (kp>>3)*15 - (kp&7)]);
    }
#endif
    float t16[16];
    #pragma unroll
    for (int i = 0; i < 16; ++i)
      t16[i] = fmaxf(fmaxf(s[i], s[i+16]), fmaxf(s[i+32], s[i+48]));
    float mx = t16[0];
    #pragma unroll
    for (int i = 1; i < 16; ++i) mx = fmaxf(mx, t16[i]);
    #pragma unroll
    for (int kp = 0; kp < 64; ++kp) s[kp] = __expf(s[kp] - mx);
    #pragma unroll
    for (int i = 0; i < 16; ++i)
      t16[i] = (s[i] + s[i+16]) + (s[i+32] + s[i+48]);
    float sum = t16[0];
    #pragma unroll
    for (int i = 1; i < 16; ++i) sum += t16[i];
    float inv = 1.0f / sum;
    float ov[8] = {0.f,0.f,0.f,0.f,0.f,0.f,0.f,0.f};
    #pragma unroll
    for (int kp = 0; kp < 64; ++kp){
      float4 va = *(const float4*)&vls[wv][kp][0];
      float4 vb = *(const float4*)&vls[wv][kp][4];
      float pp = s[kp];
      ov[0] = fmaf(pp, va.x, ov[0]); ov[1] = fmaf(pp, va.y, ov[1]);
      ov[2] = fmaf(pp, va.z, ov[2]); ov[3] = fmaf(pp, va.w, ov[3]);
      ov[4] = fmaf(pp, vb.x, ov[4]); ov[5] = fmaf(pp, vb.y, ov[5]);
      ov[6] = fmaf(pp, vb.z, ov[6]); ov[7] = fmaf(pp, vb.w, ov[7]);
    }
    u16 po[8];
    #pragma unroll
    for (int d = 0; d < 8; ++d) po[d] = f2b(ov[d] * inv);
    *(uint4*)&ols[wv][lane][0] = *(uint4*)po;
    __syncthreads();
    {
      int win = tid >> 6, d = (tid >> 3) & 7, r = tid & 7;
      u16 pk[8];
      #pragma unroll
      for (int wl = 0; wl < 8; ++wl) pk[wl] = ols[win][r*8 + wl][d];
      *(uint4*)(obuf + (size_t)(b*CC + head*8 + d)*HWSZ + (hh*8 + r)*256 + (ww0 + win)*8)
        = *(uint4*)pk;
    }
  }
}

// ---------------- u = avgpool_x(o) + avgpool_y(o) + local ----------------
__global__ void k_pool(const u16* __restrict__ obuf, u16* __restrict__ localb){
  int idx = blockIdx.x * 256 + threadIdx.x;
  int w = idx & 255, h = (idx >> 8) & 255; int bc = idx >> 16;
  const u16* oc_ = obuf + (size_t)bc * HWSZ;
  float sx = 0.f;
  #pragma unroll
  for (int u = 0; u < 8; ++u){
    int t = h - 3 + u;
    if (t == 256) t = 254;
    if ((unsigned)t <= 255u) sx += b2f(oc_[t*256 + w]);
  }
  float sy = 0.f;
  #pragma unroll
  for (int u = 0; u < 8; ++u){
    int t = w - 3 + u;
    if (t == 256) t = 254;
    if ((unsigned)t <= 255u) sy += b2f(oc_[h*256 + t]);
  }
  float res = (sx + sy) * 0.125f + b2f(localb[idx]);
  localb[idx] = f2b(res);
}

// ---------------- depthwise 8x8 conv + bn (CF in, CF out) ----------------
__launch_bounds__(256)
__global__ void k_dw(const u16* __restrict__ u_, const u16* __restrict__ dww,
                     const u16* __restrict__ g, const u16* __restrict__ bta,
                     u16* __restrict__ dwout){
  __shared__ float xt[23][24];
  __shared__ float wt[64];
  int c = blockIdx.z & 127, b = blockIdx.z >> 7;
  int h0 = blockIdx.y*16, w0 = blockIdx.x*16;
  int tid = threadIdx.x;
  const u16* up = u_ + (size_t)(b*CC + c)*HWSZ;
  for (int e = tid; e < 529; e += 256){
    int r = e / 23, q = e - r*23;
    int ih = h0 - 3 + r, iw = w0 - 3 + q;
    if (ih == 256) ih = 254;
    if (iw == 256) iw = 254;
    float v = 0.f;
    if ((unsigned)ih <= 255u && (unsigned)iw <= 255u) v = b2f(up[ih*256 + iw]);
    xt[r][q] = v;
  }
  if (tid < 64) wt[tid] = b2f(dww[c*64 + tid]);
  __syncthreads();
  int py = tid >> 4, px = tid & 15;
  float acc = 0.f;
  #pragma unroll
  for (int i = 0; i < 8; ++i)
    #pragma unroll
    for (int j = 0; j < 8; ++j)
      acc += wt[i*8+j] * xt[py+i][px+j];
  float scale = b2f(g[c]) * RSQE;
  dwout[(size_t)(b*CC + c)*HWSZ + (h0+py)*256 + (w0+px)] = f2b(acc*scale + b2f(bta[c]));
}

// ---------------- launcher ----------------
extern "C" void kernel_launch(void* const* d_in, const int* in_sizes, int n_in,
                              void* d_out, int out_size, void* d_ws, size_t ws_size,
                              hipStream_t stream) {
  char* p = (char*)d_ws;
  u16* cx     = (u16*)p; p += 33554432;   // canonical CF x -> attn output planes
  u16* xcl    = (u16*)p; p += 33554432;   // scaled CL x -> dw output CL
  u16* qkvb   = (u16*)p; p += 100663296;  // qkvw window layout -> dw output CF
  u16* cw     = (u16*)p; p += 1074176;
  float* A_h    = (float*)p; p += 65536;
  float* A_w    = (float*)p; p += 65536;
  u16*  Kwb     = (u16*)p;  p += 425984;
  float* biasK  = (float*)p; p += 1024;
  float* mh     = (float*)p; p += 262144;
  float* mw     = (float*)p; p += 262144;
  float* s_h    = (float*)p; p += 262144;
  float* s_w    = (float*)p; p += 262144;
  int* flag     = (int*)p;   p += 256;

  u16* localb = (u16*)d_out;     // d_out doubles as `local` scratch until final GEMM
  u16* qkvw   = qkvb;
  u16* obuf   = cx;              // attn output planes (cx dead after qkv gemm)
  u16* dwbuf  = qkvb;            // dw CF output (qkvw dead after attn)
  u16* dwcl   = xcl;             // dw CL output (xcl dead after qkv gemm)

  const int O_h1=0, O_w1=16384, O_fh=32768, O_fw=49152, O_l1w=65536, O_l1g=212992,
            O_l1b=213120, O_l2w=213248, O_l2g=229632, O_l2b=229760, O_hge=229888,
            O_fcw=377344, O_fcb=459264, O_qkvw=459392, O_rel=508544, O_dw=512144,
            O_pg=520336, O_pb=520464, O_pw=520592;

  k_detect<<<1, 256, 0, stream>>>((const u16*)d_in[0], flag);
  k_ingest4<<<16384, 256, 0, stream>>>(d_in[0], cx, 4194304, flag);
  PtrL pl;
  for (int i = 0; i < 19; ++i) pl.p[i] = d_in[i+1];
  k_ingest_w<<<525, 256, 0, stream>>>(pl, cw, flag);

  k_prep_A<<<64, 256, 0, stream>>>(cw+O_fh, cw+O_h1, cw+O_fw, cw+O_w1,
                                   cw+O_l1b, cw+O_l2b, cw+O_fcb, A_h, A_w, biasK);
  k_prep_K<<<64, 256, 0, stream>>>(cw+O_hge, cw+O_fcw, cw+O_l1w, cw+O_l1g,
                                   cw+O_l2w, cw+O_l2g, Kwb);
  k_means<<<dim3(128, 2), 256, 0, stream>>>(cx, mh, mw);
  k_sig<<<dim3(128, 2, 2), 256, 0, stream>>>(A_h, A_w, mh, mw, s_h, s_w);
  k_scale2cl<<<dim3(16, 1, 512), 256, 0, stream>>>(cx, s_h, s_w, xcl);

  k_conv5m<<<1024, 256, 0, stream>>>(xcl, Kwb, biasK, localb);
  k_mgemm<<<1024, 256, 0, stream>>>(xcl, cw+O_qkvw, qkvw, nullptr, flag, 3, 0);
  k_attn2<<<dim3(16, 32, 2), 128, 0, stream>>>(qkvw, cw+O_rel, obuf);
  k_pool<<<65536, 256, 0, stream>>>(obuf, localb);
  k_dw<<<dim3(16, 16, 256), 256, 0, stream>>>(localb, cw+O_dw, cw+O_pg, cw+O_pb, dwbuf);
  k_cf2cl<<<dim3(16, 1, 512), 256, 0, stream>>>(dwbuf, dwcl);
  k_mgemm<<<1024, 256, 0, stream>>>(dwcl, cw+O_pw, (u16*)d_out, (float*)d_out, flag, 1, 1);
}